// Round 1
// baseline (2470.012 us; speedup 1.0000x reference)
//
#include <hip/hip_runtime.h>
#include <math.h>

#define NEG_SLOPE 0.2f
#define BN_EPS 1e-5f

// ---- order-preserving float <-> uint encoding for atomicMax on floats ----
static __device__ __forceinline__ unsigned ford(float f){
    unsigned u = __float_as_uint(f);
    return (u & 0x80000000u) ? ~u : (u | 0x80000000u);
}
static __device__ __forceinline__ float funord(unsigned v){
    return __uint_as_float((v & 0x80000000u) ? (v ^ 0x80000000u) : ~v);
}

// =========================================================================
// GEMM h = x @ W  ([N,K] @ [K,256]) fused with per-head alpha reductions.
// 32 nodes per block; x-tile staged in LDS; W rows stream through registers
// (coalesced, L2-resident). thread t owns output channel t; wave == head.
// =========================================================================
template<int K>
__global__ __launch_bounds__(256) void gemm_alpha_kernel(
    const float* __restrict__ x, const float* __restrict__ W,
    const float* __restrict__ a_s, const float* __restrict__ a_d,
    float* __restrict__ hout, float* __restrict__ asrc, float* __restrict__ adst,
    int N)
{
    constexpr int NB = 32;
    __shared__ float xs[NB * K];
    const int t  = threadIdx.x;
    const int n0 = blockIdx.x * NB;

    for (int i = t; i < NB * K; i += 256){
        int n = n0 + i / K;
        xs[i] = (n < N) ? x[(size_t)n * K + (i % K)] : 0.f;
    }
    __syncthreads();

    float acc[NB];
#pragma unroll
    for (int n = 0; n < NB; ++n) acc[n] = 0.f;

    for (int k = 0; k < K; k += 4){
        float w0 = W[(size_t)(k+0)*256 + t];
        float w1 = W[(size_t)(k+1)*256 + t];
        float w2 = W[(size_t)(k+2)*256 + t];
        float w3 = W[(size_t)(k+3)*256 + t];
#pragma unroll
        for (int n = 0; n < NB; ++n){
            const float4 xv = *(const float4*)&xs[n*K + k];
            acc[n] = fmaf(xv.w, w3, fmaf(xv.z, w2, fmaf(xv.y, w1, fmaf(xv.x, w0, acc[n]))));
        }
    }

    const float av_s = a_s[t], av_d = a_d[t];
    const int lane = t & 63, head = t >> 6;
    for (int n = 0; n < NB; ++n){
        const int node = n0 + n;
        if (node >= N) break;                    // uniform across wave
        hout[(size_t)node*256 + t] = acc[n];
        float ps = acc[n] * av_s, pd = acc[n] * av_d;
        for (int off = 32; off >= 1; off >>= 1){
            ps += __shfl_xor(ps, off, 64);
            pd += __shfl_xor(pd, off, 64);
        }
        if (lane == 0){ asrc[node*4 + head] = ps; adst[node*4 + head] = pd; }
    }
}

// init m (ordered -inf), denom (0), acc (0)
__global__ void init_kernel(unsigned* __restrict__ mord, float* __restrict__ denom,
                            float* __restrict__ acc, int NH, int NHC)
{
    const unsigned NEG_INF_ORD = 0x007FFFFFu;   // ford(-inf)
    int i = blockIdx.x * blockDim.x + threadIdx.x;
    int stride = gridDim.x * blockDim.x;
    for (int j = i; j < NH;  j += stride){ mord[j] = NEG_INF_ORD; denom[j] = 0.f; }
    for (int j = i; j < NHC; j += stride){ acc[j] = 0.f; }
}

// pass 1 over edges: segment max of leaky_relu(alpha_src[s]+alpha_dst[d]) per head
__global__ void edge_max4(const int* __restrict__ ei, int E, int N,
                          const float* __restrict__ asrc, const float* __restrict__ adst,
                          unsigned* __restrict__ mord)
{
    int e = blockIdx.x * blockDim.x + threadIdx.x;
    if (e >= E + N) return;
    int s, d;
    if (e < E){ s = ei[e]; d = ei[E + e]; } else { s = d = e - E; }
    const float4 as = *(const float4*)&asrc[(size_t)s*4];
    const float4 ad = *(const float4*)&adst[(size_t)d*4];
    float v0 = as.x + ad.x, v1 = as.y + ad.y, v2 = as.z + ad.z, v3 = as.w + ad.w;
    v0 = v0 > 0.f ? v0 : NEG_SLOPE * v0;
    v1 = v1 > 0.f ? v1 : NEG_SLOPE * v1;
    v2 = v2 > 0.f ? v2 : NEG_SLOPE * v2;
    v3 = v3 > 0.f ? v3 : NEG_SLOPE * v3;
    atomicMax(&mord[(size_t)d*4 + 0], ford(v0));
    atomicMax(&mord[(size_t)d*4 + 1], ford(v1));
    atomicMax(&mord[(size_t)d*4 + 2], ford(v2));
    atomicMax(&mord[(size_t)d*4 + 3], ford(v3));
}

// pass 2: p = exp(e - m[dst]); denom[dst] += p; acc[dst,h,c] += p * h[src,h,c]
// one wave per edge; lane = channel within head; 4 heads per lane.
__global__ __launch_bounds__(256) void edge_acc4(
    const int* __restrict__ ei, int E, int N,
    const float* __restrict__ asrc, const float* __restrict__ adst,
    const unsigned* __restrict__ mord, const float* __restrict__ hfeat,
    float* __restrict__ denom, float* __restrict__ acc)
{
    const int wid = threadIdx.x >> 6, lane = threadIdx.x & 63;
    const int e = blockIdx.x * 4 + wid;
    if (e >= E + N) return;
    int s, d;
    if (e < E){ s = ei[e]; d = ei[E + e]; } else { s = d = e - E; }

    const float4 as = *(const float4*)&asrc[(size_t)s*4];
    const float4 ad = *(const float4*)&adst[(size_t)d*4];
    float v[4] = { as.x + ad.x, as.y + ad.y, as.z + ad.z, as.w + ad.w };
    float p[4];
#pragma unroll
    for (int h = 0; h < 4; ++h){
        float a = v[h] > 0.f ? v[h] : NEG_SLOPE * v[h];
        p[h] = __expf(a - funord(mord[(size_t)d*4 + h]));
    }
    if (lane == 0){
#pragma unroll
        for (int h = 0; h < 4; ++h) atomicAdd(&denom[(size_t)d*4 + h], p[h]);
    }
    const float* hs = &hfeat[(size_t)s * 256];
    float*       ac = &acc  [(size_t)d * 256];
#pragma unroll
    for (int h = 0; h < 4; ++h)
        atomicAdd(&ac[h*64 + lane], p[h] * hs[h*64 + lane]);
}

// normalize + bias + BN(eval) + ELU (+ optional residual)
__global__ void finalize_kernel(const float* __restrict__ acc, const float* __restrict__ denom,
    const float* __restrict__ b, const float* __restrict__ g, const float* __restrict__ be,
    const float* __restrict__ mean, const float* __restrict__ var,
    const float* __restrict__ res, float* __restrict__ outp, int N)
{
    int i = blockIdx.x * blockDim.x + threadIdx.x;
    if (i >= N * 256) return;
    int t = i & 255, n = i >> 8;
    float vv = acc[i] / denom[(size_t)n*4 + (t >> 6)] + b[t];
    vv = (vv - mean[t]) * (g[t] * rsqrtf(var[t] + BN_EPS)) + be[t];
    vv = vv > 0.f ? vv : (__expf(vv) - 1.f);
    if (res) vv += res[i];
    outp[i] = vv;
}

// ------------------------- layer 2 (heads=1, C=1) -------------------------
__global__ __launch_bounds__(256) void gemm2_kernel(
    const float* __restrict__ x, const float* __restrict__ W2,
    float* __restrict__ h2, int N)
{
    const int wid = threadIdx.x >> 6, lane = threadIdx.x & 63;
    const int n = blockIdx.x * 4 + wid;
    if (n >= N) return;
    float sum = 0.f;
#pragma unroll
    for (int i = 0; i < 4; ++i)
        sum += x[(size_t)n*256 + i*64 + lane] * W2[i*64 + lane];
    for (int off = 32; off >= 1; off >>= 1) sum += __shfl_xor(sum, off, 64);
    if (lane == 0) h2[n] = sum;
}

__global__ void edge_max2(const int* __restrict__ ei, int E, int N,
                          const float* __restrict__ h2,
                          const float* __restrict__ as2, const float* __restrict__ ad2,
                          unsigned* __restrict__ mord)
{
    int e = blockIdx.x * blockDim.x + threadIdx.x;
    if (e >= E + N) return;
    int s, d;
    if (e < E){ s = ei[e]; d = ei[E + e]; } else { s = d = e - E; }
    float a = as2[0]*h2[s] + ad2[0]*h2[d];
    a = a > 0.f ? a : NEG_SLOPE * a;
    atomicMax(&mord[d], ford(a));
}

__global__ void edge_acc2(const int* __restrict__ ei, int E, int N,
                          const float* __restrict__ h2,
                          const float* __restrict__ as2, const float* __restrict__ ad2,
                          const unsigned* __restrict__ mord,
                          float* __restrict__ denom, float* __restrict__ acc)
{
    int e = blockIdx.x * blockDim.x + threadIdx.x;
    if (e >= E + N) return;
    int s, d;
    if (e < E){ s = ei[e]; d = ei[E + e]; } else { s = d = e - E; }
    float a = as2[0]*h2[s] + ad2[0]*h2[d];
    a = a > 0.f ? a : NEG_SLOPE * a;
    float p = __expf(a - funord(mord[d]));
    atomicAdd(&denom[d], p);
    atomicAdd(&acc[d], p * h2[s]);
}

__global__ void final2_kernel(const float* __restrict__ acc, const float* __restrict__ denom,
                              const float* __restrict__ b2, float* __restrict__ out, int N)
{
    int n = blockIdx.x * blockDim.x + threadIdx.x;
    if (n < N) out[n] = acc[n] / denom[n] + b2[0];
}

// =========================================================================
extern "C" void kernel_launch(void* const* d_in, const int* in_sizes, int n_in,
                              void* d_out, int out_size, void* d_ws, size_t ws_size,
                              hipStream_t stream)
{
    const float* x   = (const float*)d_in[0];
    const int*   ei  = (const int*)  d_in[1];
    const float* W0  = (const float*)d_in[2];
    const float* as0 = (const float*)d_in[3];
    const float* ad0 = (const float*)d_in[4];
    const float* b0  = (const float*)d_in[5];
    const float* W1  = (const float*)d_in[6];
    const float* as1 = (const float*)d_in[7];
    const float* ad1 = (const float*)d_in[8];
    const float* b1  = (const float*)d_in[9];
    const float* W2  = (const float*)d_in[10];
    const float* as2 = (const float*)d_in[11];
    const float* ad2 = (const float*)d_in[12];
    const float* b2  = (const float*)d_in[13];
    const float* g0  = (const float*)d_in[14];
    const float* be0 = (const float*)d_in[15];
    const float* m0  = (const float*)d_in[16];
    const float* v0  = (const float*)d_in[17];
    const float* g1  = (const float*)d_in[18];
    const float* be1 = (const float*)d_in[19];
    const float* m1  = (const float*)d_in[20];
    const float* v1  = (const float*)d_in[21];

    const int N = in_sizes[0] / 128;
    const int E = in_sizes[1] / 2;
    const int EN = E + N;

    // ---- workspace layout ----
    char* w = (char*)d_ws;
    float*    A      = (float*)w;                 w += (size_t)N * 256 * 4;  // h feat
    float*    B      = (float*)w;                 w += (size_t)N * 256 * 4;  // post-layer0 (residual)
    float*    C      = (float*)w;                 w += (size_t)N * 256 * 4;  // accumulator
    float*    asrc   = (float*)w;                 w += (size_t)N * 4 * 4;
    float*    adst   = (float*)w;                 w += (size_t)N * 4 * 4;
    float*    denom  = (float*)w;                 w += (size_t)N * 4 * 4;
    unsigned* mord   = (unsigned*)w;              w += (size_t)N * 4 * 4;
    float*    h2     = (float*)w;                 w += (size_t)N * 4;
    float*    denom2 = (float*)w;                 w += (size_t)N * 4;
    float*    acc2   = (float*)w;                 w += (size_t)N * 4;
    unsigned* mord2  = (unsigned*)w;              w += (size_t)N * 4;

    const int gN32   = (N + 31) / 32;
    const int gEdgeT = (EN + 255) / 256;
    const int gEdgeW = (EN + 3) / 4;
    const int gNC    = (N * 256 + 255) / 256;

    // ---------------- layer 0 ----------------
    gemm_alpha_kernel<128><<<gN32, 256, 0, stream>>>(x, W0, as0, ad0, A, asrc, adst, N);
    init_kernel<<<2048, 256, 0, stream>>>(mord, denom, C, N*4, N*256);
    edge_max4<<<gEdgeT, 256, 0, stream>>>(ei, E, N, asrc, adst, mord);
    edge_acc4<<<gEdgeW, 256, 0, stream>>>(ei, E, N, asrc, adst, mord, A, denom, C);
    finalize_kernel<<<gNC, 256, 0, stream>>>(C, denom, b0, g0, be0, m0, v0, nullptr, B, N);

    // ---------------- layer 1 ----------------
    gemm_alpha_kernel<256><<<gN32, 256, 0, stream>>>(B, W1, as1, ad1, A, asrc, adst, N);
    init_kernel<<<2048, 256, 0, stream>>>(mord, denom, C, N*4, N*256);
    edge_max4<<<gEdgeT, 256, 0, stream>>>(ei, E, N, asrc, adst, mord);
    edge_acc4<<<gEdgeW, 256, 0, stream>>>(ei, E, N, asrc, adst, mord, A, denom, C);
    finalize_kernel<<<gNC, 256, 0, stream>>>(C, denom, b1, g1, be1, m1, v1, B, A, N);

    // ---------------- layer 2 ----------------
    gemm2_kernel<<<(N + 3) / 4, 256, 0, stream>>>(A, W2, h2, N);
    init_kernel<<<512, 256, 0, stream>>>(mord2, denom2, acc2, N, N);
    edge_max2<<<gEdgeT, 256, 0, stream>>>(ei, E, N, h2, as2, ad2, mord2);
    edge_acc2<<<gEdgeT, 256, 0, stream>>>(ei, E, N, h2, as2, ad2, mord2, denom2, acc2);
    final2_kernel<<<(N + 255) / 256, 256, 0, stream>>>(acc2, denom2, b2, (float*)d_out, N);
}

// Round 2
// 812.589 us; speedup vs baseline: 3.0397x; 3.0397x over previous
//
#include <hip/hip_runtime.h>
#include <math.h>

#define NEG_SLOPE 0.2f
#define BN_EPS 1e-5f

// =========================================================================
// GEMM h = x @ W  ([N,K] @ [K,256]) fused with per-head alpha reductions.
// 32 nodes per block; x-tile staged in LDS; W rows stream through registers
// (coalesced, L2-resident). thread t owns output channel t; wave == head.
// =========================================================================
template<int K>
__global__ __launch_bounds__(256) void gemm_alpha_kernel(
    const float* __restrict__ x, const float* __restrict__ W,
    const float* __restrict__ a_s, const float* __restrict__ a_d,
    float* __restrict__ hout, float* __restrict__ asrc, float* __restrict__ adst,
    int N)
{
    constexpr int NB = 32;
    __shared__ float xs[NB * K];
    const int t  = threadIdx.x;
    const int n0 = blockIdx.x * NB;

    for (int i = t; i < NB * K; i += 256){
        int n = n0 + i / K;
        xs[i] = (n < N) ? x[(size_t)n * K + (i % K)] : 0.f;
    }
    __syncthreads();

    float acc[NB];
#pragma unroll
    for (int n = 0; n < NB; ++n) acc[n] = 0.f;

    for (int k = 0; k < K; k += 4){
        float w0 = W[(size_t)(k+0)*256 + t];
        float w1 = W[(size_t)(k+1)*256 + t];
        float w2 = W[(size_t)(k+2)*256 + t];
        float w3 = W[(size_t)(k+3)*256 + t];
#pragma unroll
        for (int n = 0; n < NB; ++n){
            const float4 xv = *(const float4*)&xs[n*K + k];
            acc[n] = fmaf(xv.w, w3, fmaf(xv.z, w2, fmaf(xv.y, w1, fmaf(xv.x, w0, acc[n]))));
        }
    }

    const float av_s = a_s[t], av_d = a_d[t];
    const int lane = t & 63, head = t >> 6;
    for (int n = 0; n < NB; ++n){
        const int node = n0 + n;
        if (node >= N) break;                    // uniform across wave
        hout[(size_t)node*256 + t] = acc[n];
        float ps = acc[n] * av_s, pd = acc[n] * av_d;
        for (int off = 32; off >= 1; off >>= 1){
            ps += __shfl_xor(ps, off, 64);
            pd += __shfl_xor(pd, off, 64);
        }
        if (lane == 0){ asrc[node*4 + head] = ps; adst[node*4 + head] = pd; }
    }
}

// ============================ CSR build (once) ============================
__global__ void deg_init_kernel(int* __restrict__ deg, int N){
    int i = blockIdx.x * blockDim.x + threadIdx.x;
    if (i < N) deg[i] = 1;                        // self-loop
}

__global__ void deg_hist_kernel(const int* __restrict__ ei, int E, int* __restrict__ deg){
    int e = blockIdx.x * blockDim.x + threadIdx.x;
    if (e < E) atomicAdd(&deg[ei[E + e]], 1);
}

// single-block exclusive scan over deg -> row[0..N], cursor copy
__global__ __launch_bounds__(256) void scan_kernel(const int* __restrict__ deg,
                                                   int* __restrict__ row,
                                                   int* __restrict__ cursor, int N)
{
    __shared__ int sums[256];
    const int t = threadIdx.x;
    const int chunk = (N + 255) / 256;
    const int b = t * chunk, e = min(b + chunk, N);
    int s = 0;
    for (int i = b; i < e; ++i) s += deg[i];
    sums[t] = s; __syncthreads();
    for (int off = 1; off < 256; off <<= 1){
        int v = (t >= off) ? sums[t - off] : 0;
        __syncthreads();
        sums[t] += v;
        __syncthreads();
    }
    int pre = (t == 0) ? 0 : sums[t - 1];
    for (int i = b; i < e; ++i){ row[i] = pre; cursor[i] = pre; pre += deg[i]; }
    if (t == 255) row[N] = sums[255];
}

__global__ void scatter_kernel(const int* __restrict__ ei, int E, int N,
                               int* __restrict__ cursor, int* __restrict__ csr)
{
    int e = blockIdx.x * blockDim.x + threadIdx.x;
    if (e >= E + N) return;
    int s, d;
    if (e < E){ s = ei[e]; d = ei[E + e]; } else { s = d = e - E; }
    int pos = atomicAdd(&cursor[d], 1);
    csr[pos] = s;
}

// =========================================================================
// Gather-aggregate per destination node: one wave per node.
// pass1: lane-parallel segment max; pass2: p=exp(e-m), acc += p*h[src].
// Fused epilogue: /denom + bias + BN(eval) + ELU (+ residual).
// =========================================================================
__global__ __launch_bounds__(256) void agg4_kernel(
    const int* __restrict__ row, const int* __restrict__ csr,
    const float* __restrict__ asrc, const float* __restrict__ adst,
    const float* __restrict__ h,
    const float* __restrict__ b, const float* __restrict__ g,
    const float* __restrict__ be, const float* __restrict__ mean,
    const float* __restrict__ var,
    const float* __restrict__ res, float* __restrict__ outp, int N)
{
    const int wid = threadIdx.x >> 6, lane = threadIdx.x & 63;
    const int node = blockIdx.x * 4 + wid;
    if (node >= N) return;
    const int beg = row[node], end = row[node + 1];

    const float4 ad = *(const float4*)&adst[(size_t)node * 4];

    // ---- pass 1: per-head max, lane-parallel over edges ----
    float m0 = -1e30f, m1 = -1e30f, m2 = -1e30f, m3 = -1e30f;
    for (int i = beg + lane; i < end; i += 64){
        const int s = csr[i];
        const float4 as = *(const float4*)&asrc[(size_t)s * 4];
        float v0 = as.x + ad.x, v1 = as.y + ad.y, v2 = as.z + ad.z, v3 = as.w + ad.w;
        v0 = v0 > 0.f ? v0 : NEG_SLOPE * v0;
        v1 = v1 > 0.f ? v1 : NEG_SLOPE * v1;
        v2 = v2 > 0.f ? v2 : NEG_SLOPE * v2;
        v3 = v3 > 0.f ? v3 : NEG_SLOPE * v3;
        m0 = fmaxf(m0, v0); m1 = fmaxf(m1, v1);
        m2 = fmaxf(m2, v2); m3 = fmaxf(m3, v3);
    }
    for (int off = 32; off >= 1; off >>= 1){
        m0 = fmaxf(m0, __shfl_xor(m0, off, 64));
        m1 = fmaxf(m1, __shfl_xor(m1, off, 64));
        m2 = fmaxf(m2, __shfl_xor(m2, off, 64));
        m3 = fmaxf(m3, __shfl_xor(m3, off, 64));
    }

    // ---- pass 2: weighted gather-accumulate ----
    float a0 = 0.f, a1 = 0.f, a2 = 0.f, a3 = 0.f;
    float d0 = 0.f, d1 = 0.f, d2 = 0.f, d3 = 0.f;
    for (int i = beg; i < end; ++i){
        const int s = csr[i];                     // same addr all lanes (broadcast)
        const float4 as = *(const float4*)&asrc[(size_t)s * 4];
        float v0 = as.x + ad.x, v1 = as.y + ad.y, v2 = as.z + ad.z, v3 = as.w + ad.w;
        v0 = v0 > 0.f ? v0 : NEG_SLOPE * v0;
        v1 = v1 > 0.f ? v1 : NEG_SLOPE * v1;
        v2 = v2 > 0.f ? v2 : NEG_SLOPE * v2;
        v3 = v3 > 0.f ? v3 : NEG_SLOPE * v3;
        const float p0 = __expf(v0 - m0), p1 = __expf(v1 - m1);
        const float p2 = __expf(v2 - m2), p3 = __expf(v3 - m3);
        const float* hs = &h[(size_t)s * 256];
        a0 = fmaf(p0, hs[lane],       a0);
        a1 = fmaf(p1, hs[64  + lane], a1);
        a2 = fmaf(p2, hs[128 + lane], a2);
        a3 = fmaf(p3, hs[192 + lane], a3);
        d0 += p0; d1 += p1; d2 += p2; d3 += p3;
    }

    // ---- fused epilogue ----
    float* o = &outp[(size_t)node * 256];
    const float vals[4] = { a0 / d0, a1 / d1, a2 / d2, a3 / d3 };
#pragma unroll
    for (int hd = 0; hd < 4; ++hd){
        const int c = hd * 64 + lane;
        float vv = vals[hd] + b[c];
        vv = (vv - mean[c]) * (g[c] * rsqrtf(var[c] + BN_EPS)) + be[c];
        vv = vv > 0.f ? vv : (__expf(vv) - 1.f);
        if (res) vv += res[(size_t)node * 256 + c];
        o[c] = vv;
    }
}

// ------------------------- layer 2 (heads=1, C=1) -------------------------
__global__ __launch_bounds__(256) void gemm2_kernel(
    const float* __restrict__ x, const float* __restrict__ W2,
    float* __restrict__ h2, int N)
{
    const int wid = threadIdx.x >> 6, lane = threadIdx.x & 63;
    const int n = blockIdx.x * 4 + wid;
    if (n >= N) return;
    float sum = 0.f;
#pragma unroll
    for (int i = 0; i < 4; ++i)
        sum += x[(size_t)n*256 + i*64 + lane] * W2[i*64 + lane];
    for (int off = 32; off >= 1; off >>= 1) sum += __shfl_xor(sum, off, 64);
    if (lane == 0) h2[n] = sum;
}

__global__ void agg2_kernel(const int* __restrict__ row, const int* __restrict__ csr,
                            const float* __restrict__ h2,
                            const float* __restrict__ as2, const float* __restrict__ ad2,
                            const float* __restrict__ b2, float* __restrict__ out, int N)
{
    const int n = blockIdx.x * blockDim.x + threadIdx.x;
    if (n >= N) return;
    const float A_s = as2[0];
    const float hd  = h2[n] * ad2[0];
    const int beg = row[n], end = row[n + 1];
    float m = -1e30f;
    for (int i = beg; i < end; ++i){
        float a = fmaf(A_s, h2[csr[i]], hd);
        a = a > 0.f ? a : NEG_SLOPE * a;
        m = fmaxf(m, a);
    }
    float den = 0.f, acc = 0.f;
    for (int i = beg; i < end; ++i){
        const float hv = h2[csr[i]];
        float a = fmaf(A_s, hv, hd);
        a = a > 0.f ? a : NEG_SLOPE * a;
        const float p = __expf(a - m);
        den += p; acc = fmaf(p, hv, acc);
    }
    out[n] = acc / den + b2[0];
}

// =========================================================================
extern "C" void kernel_launch(void* const* d_in, const int* in_sizes, int n_in,
                              void* d_out, int out_size, void* d_ws, size_t ws_size,
                              hipStream_t stream)
{
    const float* x   = (const float*)d_in[0];
    const int*   ei  = (const int*)  d_in[1];
    const float* W0  = (const float*)d_in[2];
    const float* as0 = (const float*)d_in[3];
    const float* ad0 = (const float*)d_in[4];
    const float* b0  = (const float*)d_in[5];
    const float* W1  = (const float*)d_in[6];
    const float* as1 = (const float*)d_in[7];
    const float* ad1 = (const float*)d_in[8];
    const float* b1  = (const float*)d_in[9];
    const float* W2  = (const float*)d_in[10];
    const float* as2 = (const float*)d_in[11];
    const float* ad2 = (const float*)d_in[12];
    const float* b2  = (const float*)d_in[13];
    const float* g0  = (const float*)d_in[14];
    const float* be0 = (const float*)d_in[15];
    const float* m0  = (const float*)d_in[16];
    const float* v0  = (const float*)d_in[17];
    const float* g1  = (const float*)d_in[18];
    const float* be1 = (const float*)d_in[19];
    const float* m1  = (const float*)d_in[20];
    const float* v1  = (const float*)d_in[21];

    const int N = in_sizes[0] / 128;
    const int E = in_sizes[1] / 2;
    const int EN = E + N;

    // ---- workspace layout ----
    char* w = (char*)d_ws;
    float*    H      = (float*)w;   w += (size_t)N * 256 * 4;  // h features
    float*    P0     = (float*)w;   w += (size_t)N * 256 * 4;  // layer0 out (residual)
    float*    P1     = (float*)w;   w += (size_t)N * 256 * 4;  // layer1 out
    float*    asrc   = (float*)w;   w += (size_t)N * 4 * 4;
    float*    adst   = (float*)w;   w += (size_t)N * 4 * 4;
    int*      deg    = (int*)w;     w += (size_t)N * 4;
    int*      rowp   = (int*)w;     w += (size_t)(N + 1) * 4;
    int*      cursor = (int*)w;     w += (size_t)N * 4;
    int*      csr    = (int*)w;     w += (size_t)EN * 4;
    float*    h2     = (float*)w;   w += (size_t)N * 4;

    const int gN32  = (N + 31) / 32;
    const int gN4   = (N + 3) / 4;
    const int gNt   = (N + 255) / 256;
    const int gE    = (E + 255) / 256;
    const int gEN   = (EN + 255) / 256;

    // ---------------- CSR build (shared by all layers) ----------------
    deg_init_kernel<<<gNt, 256, 0, stream>>>(deg, N);
    deg_hist_kernel<<<gE, 256, 0, stream>>>(ei, E, deg);
    scan_kernel<<<1, 256, 0, stream>>>(deg, rowp, cursor, N);
    scatter_kernel<<<gEN, 256, 0, stream>>>(ei, E, N, cursor, csr);

    // ---------------- layer 0 ----------------
    gemm_alpha_kernel<128><<<gN32, 256, 0, stream>>>(x, W0, as0, ad0, H, asrc, adst, N);
    agg4_kernel<<<gN4, 256, 0, stream>>>(rowp, csr, asrc, adst, H,
                                         b0, g0, be0, m0, v0, nullptr, P0, N);

    // ---------------- layer 1 ----------------
    gemm_alpha_kernel<256><<<gN32, 256, 0, stream>>>(P0, W1, as1, ad1, H, asrc, adst, N);
    agg4_kernel<<<gN4, 256, 0, stream>>>(rowp, csr, asrc, adst, H,
                                         b1, g1, be1, m1, v1, P0, P1, N);

    // ---------------- layer 2 ----------------
    gemm2_kernel<<<gN4, 256, 0, stream>>>(P1, W2, h2, N);
    agg2_kernel<<<gNt, 256, 0, stream>>>(rowp, csr, h2, as2, ad2, b2, (float*)d_out, N);
}

// Round 3
// 627.671 us; speedup vs baseline: 3.9352x; 1.2946x over previous
//
#include <hip/hip_runtime.h>
#include <math.h>

#define NEG_SLOPE 0.2f
#define BN_EPS 1e-5f

static __device__ __forceinline__ unsigned short f2bf(float f){
    unsigned u = __float_as_uint(f);
    u += 0x7FFFu + ((u >> 16) & 1u);          // round-to-nearest-even
    return (unsigned short)(u >> 16);
}
static __device__ __forceinline__ float bf2f(unsigned short v){
    return __uint_as_float((unsigned)v << 16);
}

// =========================================================================
// GEMM h = x @ W  ([N,K] @ [K,256]) + per-head alpha reductions.
// Block = 256 thr = 4 waves; 32-node x-tile in LDS; wave w owns nodes w*8..w*8+7.
// Lane l owns channels {c4*64+l, c4=0..3} (one channel per head).
// Per k-step-of-4: 8 broadcast ds_read_b128 vs 128 FMA/thread -> VALU-bound.
// h output written as packed bf16 [N][64][4] (channel-major, head-minor).
// =========================================================================
template<int K>
__global__ __launch_bounds__(256) void gemm_alpha_kernel(
    const float* __restrict__ x, const float* __restrict__ W,
    const float* __restrict__ a_s, const float* __restrict__ a_d,
    unsigned short* __restrict__ hout,
    float* __restrict__ asrc, float* __restrict__ adst, int N)
{
    constexpr int NB = 32;
    __shared__ float xs[NB * K];
    const int t = threadIdx.x, lane = t & 63, wid = t >> 6;
    const int n0 = blockIdx.x * NB;

    for (int i = t; i < NB * K; i += 256){
        int n = n0 + i / K;
        xs[i] = (n < N) ? x[(size_t)n * K + (i % K)] : 0.f;
    }
    __syncthreads();

    float acc[8][4];
#pragma unroll
    for (int n = 0; n < 8; ++n)
#pragma unroll
        for (int c = 0; c < 4; ++c) acc[n][c] = 0.f;

    for (int k = 0; k < K; k += 4){
        float w[4][4];
#pragma unroll
        for (int j = 0; j < 4; ++j)
#pragma unroll
            for (int c = 0; c < 4; ++c)
                w[j][c] = W[(size_t)(k + j) * 256 + c * 64 + lane];
#pragma unroll
        for (int n = 0; n < 8; ++n){
            const float4 xv = *(const float4*)&xs[(wid * 8 + n) * K + k];
#pragma unroll
            for (int c = 0; c < 4; ++c){
                acc[n][c] = fmaf(xv.x, w[0][c], acc[n][c]);
                acc[n][c] = fmaf(xv.y, w[1][c], acc[n][c]);
                acc[n][c] = fmaf(xv.z, w[2][c], acc[n][c]);
                acc[n][c] = fmaf(xv.w, w[3][c], acc[n][c]);
            }
        }
    }

    float asv[4], adv[4];
#pragma unroll
    for (int c = 0; c < 4; ++c){
        asv[c] = a_s[c * 64 + lane];
        adv[c] = a_d[c * 64 + lane];
    }

    for (int n = 0; n < 8; ++n){
        const int node = n0 + wid * 8 + n;
        if (node >= N) break;                    // uniform across wave
        ushort4 hp;
        hp.x = f2bf(acc[n][0]); hp.y = f2bf(acc[n][1]);
        hp.z = f2bf(acc[n][2]); hp.w = f2bf(acc[n][3]);
        *(ushort4*)&hout[(size_t)node * 256 + lane * 4] = hp;

        float s0 = acc[n][0]*asv[0], s1 = acc[n][1]*asv[1];
        float s2 = acc[n][2]*asv[2], s3 = acc[n][3]*asv[3];
        float d0 = acc[n][0]*adv[0], d1 = acc[n][1]*adv[1];
        float d2 = acc[n][2]*adv[2], d3 = acc[n][3]*adv[3];
        for (int off = 32; off >= 1; off >>= 1){
            s0 += __shfl_xor(s0, off, 64); s1 += __shfl_xor(s1, off, 64);
            s2 += __shfl_xor(s2, off, 64); s3 += __shfl_xor(s3, off, 64);
            d0 += __shfl_xor(d0, off, 64); d1 += __shfl_xor(d1, off, 64);
            d2 += __shfl_xor(d2, off, 64); d3 += __shfl_xor(d3, off, 64);
        }
        if (lane == 0){
            *(float4*)&asrc[(size_t)node * 4] = make_float4(s0, s1, s2, s3);
            *(float4*)&adst[(size_t)node * 4] = make_float4(d0, d1, d2, d3);
        }
    }
}

// ============================ CSR build (once) ============================
__global__ void deg_init_kernel(int* __restrict__ deg, int N){
    int i = blockIdx.x * blockDim.x + threadIdx.x;
    if (i < N) deg[i] = 1;                        // self-loop
}

__global__ void deg_hist_kernel(const int* __restrict__ ei, int E, int* __restrict__ deg){
    int e = blockIdx.x * blockDim.x + threadIdx.x;
    if (e < E) atomicAdd(&deg[ei[E + e]], 1);
}

__global__ __launch_bounds__(256) void scan_kernel(const int* __restrict__ deg,
                                                   int* __restrict__ row,
                                                   int* __restrict__ cursor, int N)
{
    __shared__ int sums[256];
    const int t = threadIdx.x;
    const int chunk = (N + 255) / 256;
    const int b = t * chunk, e = min(b + chunk, N);
    int s = 0;
    for (int i = b; i < e; ++i) s += deg[i];
    sums[t] = s; __syncthreads();
    for (int off = 1; off < 256; off <<= 1){
        int v = (t >= off) ? sums[t - off] : 0;
        __syncthreads();
        sums[t] += v;
        __syncthreads();
    }
    int pre = (t == 0) ? 0 : sums[t - 1];
    for (int i = b; i < e; ++i){ row[i] = pre; cursor[i] = pre; pre += deg[i]; }
    if (t == 255) row[N] = sums[255];
}

__global__ void scatter_kernel(const int* __restrict__ ei, int E, int N,
                               int* __restrict__ cursor, int* __restrict__ csr)
{
    int e = blockIdx.x * blockDim.x + threadIdx.x;
    if (e >= E + N) return;
    int s, d;
    if (e < E){ s = ei[e]; d = ei[E + e]; } else { s = d = e - E; }
    int pos = atomicAdd(&cursor[d], 1);
    csr[pos] = s;
}

// =========================================================================
// Gather-aggregate per destination node: one wave per node. h is packed bf16.
// =========================================================================
__global__ __launch_bounds__(256) void agg4_kernel(
    const int* __restrict__ row, const int* __restrict__ csr,
    const float* __restrict__ asrc, const float* __restrict__ adst,
    const unsigned short* __restrict__ h,
    const float* __restrict__ b, const float* __restrict__ g,
    const float* __restrict__ be, const float* __restrict__ mean,
    const float* __restrict__ var,
    const float* __restrict__ res, float* __restrict__ outp, int N)
{
    const int wid = threadIdx.x >> 6, lane = threadIdx.x & 63;
    const int node = blockIdx.x * 4 + wid;
    if (node >= N) return;
    const int beg = row[node], end = row[node + 1];

    const float4 ad = *(const float4*)&adst[(size_t)node * 4];

    // ---- pass 1: per-head max, lane-parallel over edges ----
    float m0 = -1e30f, m1 = -1e30f, m2 = -1e30f, m3 = -1e30f;
    for (int i = beg + lane; i < end; i += 64){
        const int s = csr[i];
        const float4 as = *(const float4*)&asrc[(size_t)s * 4];
        float v0 = as.x + ad.x, v1 = as.y + ad.y, v2 = as.z + ad.z, v3 = as.w + ad.w;
        v0 = v0 > 0.f ? v0 : NEG_SLOPE * v0;
        v1 = v1 > 0.f ? v1 : NEG_SLOPE * v1;
        v2 = v2 > 0.f ? v2 : NEG_SLOPE * v2;
        v3 = v3 > 0.f ? v3 : NEG_SLOPE * v3;
        m0 = fmaxf(m0, v0); m1 = fmaxf(m1, v1);
        m2 = fmaxf(m2, v2); m3 = fmaxf(m3, v3);
    }
    for (int off = 32; off >= 1; off >>= 1){
        m0 = fmaxf(m0, __shfl_xor(m0, off, 64));
        m1 = fmaxf(m1, __shfl_xor(m1, off, 64));
        m2 = fmaxf(m2, __shfl_xor(m2, off, 64));
        m3 = fmaxf(m3, __shfl_xor(m3, off, 64));
    }

    // ---- pass 2: weighted gather-accumulate (2-unrolled for MLP) ----
    float a0 = 0.f, a1 = 0.f, a2 = 0.f, a3 = 0.f;
    float d0 = 0.f, d1 = 0.f, d2 = 0.f, d3 = 0.f;

#define EDGE_BODY(sv)                                                          \
    {                                                                          \
        const int s_ = (sv);                                                   \
        const float4 as_ = *(const float4*)&asrc[(size_t)s_ * 4];              \
        const ushort4 hv_ = *(const ushort4*)&h[(size_t)s_ * 256 + lane * 4];  \
        float v0_ = as_.x + ad.x, v1_ = as_.y + ad.y;                          \
        float v2_ = as_.z + ad.z, v3_ = as_.w + ad.w;                          \
        v0_ = v0_ > 0.f ? v0_ : NEG_SLOPE * v0_;                               \
        v1_ = v1_ > 0.f ? v1_ : NEG_SLOPE * v1_;                               \
        v2_ = v2_ > 0.f ? v2_ : NEG_SLOPE * v2_;                               \
        v3_ = v3_ > 0.f ? v3_ : NEG_SLOPE * v3_;                               \
        const float p0_ = __expf(v0_ - m0), p1_ = __expf(v1_ - m1);            \
        const float p2_ = __expf(v2_ - m2), p3_ = __expf(v3_ - m3);            \
        a0 = fmaf(p0_, bf2f(hv_.x), a0); a1 = fmaf(p1_, bf2f(hv_.y), a1);      \
        a2 = fmaf(p2_, bf2f(hv_.z), a2); a3 = fmaf(p3_, bf2f(hv_.w), a3);      \
        d0 += p0_; d1 += p1_; d2 += p2_; d3 += p3_;                            \
    }

    int i = beg;
    for (; i + 2 <= end; i += 2){
        const int sA = csr[i], sB = csr[i + 1];
        EDGE_BODY(sA);
        EDGE_BODY(sB);
    }
    for (; i < end; ++i) EDGE_BODY(csr[i]);
#undef EDGE_BODY

    // ---- fused epilogue ----
    float* o = &outp[(size_t)node * 256];
    const float vals[4] = { a0 / d0, a1 / d1, a2 / d2, a3 / d3 };
#pragma unroll
    for (int hd = 0; hd < 4; ++hd){
        const int c = hd * 64 + lane;
        float vv = vals[hd] + b[c];
        vv = (vv - mean[c]) * (g[c] * rsqrtf(var[c] + BN_EPS)) + be[c];
        vv = vv > 0.f ? vv : (__expf(vv) - 1.f);
        if (res) vv += res[(size_t)node * 256 + c];
        o[c] = vv;
    }
}

// ------------------------- layer 2 (heads=1, C=1) -------------------------
__global__ __launch_bounds__(256) void gemm2_kernel(
    const float* __restrict__ x, const float* __restrict__ W2,
    float* __restrict__ h2, int N)
{
    const int wid = threadIdx.x >> 6, lane = threadIdx.x & 63;
    const int n = blockIdx.x * 4 + wid;
    if (n >= N) return;
    float sum = 0.f;
#pragma unroll
    for (int i = 0; i < 4; ++i)
        sum += x[(size_t)n*256 + i*64 + lane] * W2[i*64 + lane];
    for (int off = 32; off >= 1; off >>= 1) sum += __shfl_xor(sum, off, 64);
    if (lane == 0) h2[n] = sum;
}

__global__ void agg2_kernel(const int* __restrict__ row, const int* __restrict__ csr,
                            const float* __restrict__ h2,
                            const float* __restrict__ as2, const float* __restrict__ ad2,
                            const float* __restrict__ b2, float* __restrict__ out, int N)
{
    const int n = blockIdx.x * blockDim.x + threadIdx.x;
    if (n >= N) return;
    const float A_s = as2[0];
    const float hd  = h2[n] * ad2[0];
    const int beg = row[n], end = row[n + 1];
    float m = -1e30f;
    for (int i = beg; i < end; ++i){
        float a = fmaf(A_s, h2[csr[i]], hd);
        a = a > 0.f ? a : NEG_SLOPE * a;
        m = fmaxf(m, a);
    }
    float den = 0.f, acc = 0.f;
    for (int i = beg; i < end; ++i){
        const float hv = h2[csr[i]];
        float a = fmaf(A_s, hv, hd);
        a = a > 0.f ? a : NEG_SLOPE * a;
        const float p = __expf(a - m);
        den += p; acc = fmaf(p, hv, acc);
    }
    out[n] = acc / den + b2[0];
}

// =========================================================================
extern "C" void kernel_launch(void* const* d_in, const int* in_sizes, int n_in,
                              void* d_out, int out_size, void* d_ws, size_t ws_size,
                              hipStream_t stream)
{
    const float* x   = (const float*)d_in[0];
    const int*   ei  = (const int*)  d_in[1];
    const float* W0  = (const float*)d_in[2];
    const float* as0 = (const float*)d_in[3];
    const float* ad0 = (const float*)d_in[4];
    const float* b0  = (const float*)d_in[5];
    const float* W1  = (const float*)d_in[6];
    const float* as1 = (const float*)d_in[7];
    const float* ad1 = (const float*)d_in[8];
    const float* b1  = (const float*)d_in[9];
    const float* W2  = (const float*)d_in[10];
    const float* as2 = (const float*)d_in[11];
    const float* ad2 = (const float*)d_in[12];
    const float* b2  = (const float*)d_in[13];
    const float* g0  = (const float*)d_in[14];
    const float* be0 = (const float*)d_in[15];
    const float* m0  = (const float*)d_in[16];
    const float* v0  = (const float*)d_in[17];
    const float* g1  = (const float*)d_in[18];
    const float* be1 = (const float*)d_in[19];
    const float* m1  = (const float*)d_in[20];
    const float* v1  = (const float*)d_in[21];

    const int N = in_sizes[0] / 128;
    const int E = in_sizes[1] / 2;
    const int EN = E + N;

    // ---- workspace layout ----
    char* w = (char*)d_ws;
    unsigned short* H = (unsigned short*)w;  w += (size_t)N * 256 * 2;  // bf16 packed h
    float*    P0     = (float*)w;   w += (size_t)N * 256 * 4;  // layer0 out (residual)
    float*    P1     = (float*)w;   w += (size_t)N * 256 * 4;  // layer1 out
    float*    asrc   = (float*)w;   w += (size_t)N * 4 * 4;
    float*    adst   = (float*)w;   w += (size_t)N * 4 * 4;
    int*      deg    = (int*)w;     w += (size_t)N * 4;
    int*      rowp   = (int*)w;     w += (size_t)(N + 1) * 4;
    int*      cursor = (int*)w;     w += (size_t)N * 4;
    int*      csr    = (int*)w;     w += (size_t)EN * 4;
    float*    h2     = (float*)w;   w += (size_t)N * 4;

    const int gN32  = (N + 31) / 32;
    const int gN4   = (N + 3) / 4;
    const int gNt   = (N + 255) / 256;
    const int gE    = (E + 255) / 256;
    const int gEN   = (EN + 255) / 256;

    // ---------------- CSR build (shared by all layers) ----------------
    deg_init_kernel<<<gNt, 256, 0, stream>>>(deg, N);
    deg_hist_kernel<<<gE, 256, 0, stream>>>(ei, E, deg);
    scan_kernel<<<1, 256, 0, stream>>>(deg, rowp, cursor, N);
    scatter_kernel<<<gEN, 256, 0, stream>>>(ei, E, N, cursor, csr);

    // ---------------- layer 0 ----------------
    gemm_alpha_kernel<128><<<gN32, 256, 0, stream>>>(x, W0, as0, ad0, H, asrc, adst, N);
    agg4_kernel<<<gN4, 256, 0, stream>>>(rowp, csr, asrc, adst, H,
                                         b0, g0, be0, m0, v0, nullptr, P0, N);

    // ---------------- layer 1 ----------------
    gemm_alpha_kernel<256><<<gN32, 256, 0, stream>>>(P0, W1, as1, ad1, H, asrc, adst, N);
    agg4_kernel<<<gN4, 256, 0, stream>>>(rowp, csr, asrc, adst, H,
                                         b1, g1, be1, m1, v1, P0, P1, N);

    // ---------------- layer 2 ----------------
    gemm2_kernel<<<gN4, 256, 0, stream>>>(P1, W2, h2, N);
    agg2_kernel<<<gNt, 256, 0, stream>>>(rowp, csr, h2, as2, ad2, b2, (float*)d_out, N);
}

// Round 4
// 527.522 us; speedup vs baseline: 4.6823x; 1.1898x over previous
//
#include <hip/hip_runtime.h>
#include <math.h>

#define NEG_SLOPE 0.2f
#define BN_EPS 1e-5f

static __device__ __forceinline__ unsigned short f2bf(float f){
    unsigned u = __float_as_uint(f);
    u += 0x7FFFu + ((u >> 16) & 1u);          // round-to-nearest-even
    return (unsigned short)(u >> 16);
}
static __device__ __forceinline__ float bf2f(unsigned short v){
    return __uint_as_float((unsigned)v << 16);
}

// =========================================================================
// GEMM h = x @ W  ([N,K] @ [K,256]) + per-head alpha reductions.
// Block = 256 thr = 4 waves; 32-node x-tile in LDS; wave w owns nodes w*8..w*8+7.
// Lane l owns channels {c4*64+l, c4=0..3} (one channel per head).
// W tile register-double-buffered: load k+4 while FMA-ing k (hide L2 latency).
// h output written as packed bf16 [N][64][4] (channel-major, head-minor).
// =========================================================================
template<int K>
__global__ __launch_bounds__(256) void gemm_alpha_kernel(
    const float* __restrict__ x, const float* __restrict__ W,
    const float* __restrict__ a_s, const float* __restrict__ a_d,
    unsigned short* __restrict__ hout,
    float* __restrict__ asrc, float* __restrict__ adst, int N)
{
    constexpr int NB = 32;
    __shared__ float xs[NB * K];
    const int t = threadIdx.x, lane = t & 63, wid = t >> 6;
    const int n0 = blockIdx.x * NB;

    for (int i = t; i < NB * K; i += 256){
        int n = n0 + i / K;
        xs[i] = (n < N) ? x[(size_t)n * K + (i % K)] : 0.f;
    }
    __syncthreads();

    float acc[8][4];
#pragma unroll
    for (int n = 0; n < 8; ++n)
#pragma unroll
        for (int c = 0; c < 4; ++c) acc[n][c] = 0.f;

    float wA[16], wB[16];

    auto loadW = [&](float* dst, int k){
#pragma unroll
        for (int j = 0; j < 4; ++j)
#pragma unroll
            for (int c = 0; c < 4; ++c)
                dst[j * 4 + c] = W[(size_t)(k + j) * 256 + c * 64 + lane];
    };
    auto fmaStep = [&](const float* wr, int kk){
#pragma unroll
        for (int n = 0; n < 8; ++n){
            const float4 xv = *(const float4*)&xs[(wid * 8 + n) * K + kk];
#pragma unroll
            for (int c = 0; c < 4; ++c){
                acc[n][c] = fmaf(xv.x, wr[0 * 4 + c], acc[n][c]);
                acc[n][c] = fmaf(xv.y, wr[1 * 4 + c], acc[n][c]);
                acc[n][c] = fmaf(xv.z, wr[2 * 4 + c], acc[n][c]);
                acc[n][c] = fmaf(xv.w, wr[3 * 4 + c], acc[n][c]);
            }
        }
    };

    loadW(wA, 0);
    int k = 0;
    for (; k + 8 < K; k += 8){
        loadW(wB, k + 4);
        fmaStep(wA, k);
        loadW(wA, k + 8);
        fmaStep(wB, k + 4);
    }
    loadW(wB, k + 4);          // k == K-8
    fmaStep(wA, k);
    fmaStep(wB, k + 4);

    float asv[4], adv[4];
#pragma unroll
    for (int c = 0; c < 4; ++c){
        asv[c] = a_s[c * 64 + lane];
        adv[c] = a_d[c * 64 + lane];
    }

    for (int n = 0; n < 8; ++n){
        const int node = n0 + wid * 8 + n;
        if (node >= N) break;                    // uniform across wave
        ushort4 hp;
        hp.x = f2bf(acc[n][0]); hp.y = f2bf(acc[n][1]);
        hp.z = f2bf(acc[n][2]); hp.w = f2bf(acc[n][3]);
        *(ushort4*)&hout[(size_t)node * 256 + lane * 4] = hp;

        float s0 = acc[n][0]*asv[0], s1 = acc[n][1]*asv[1];
        float s2 = acc[n][2]*asv[2], s3 = acc[n][3]*asv[3];
        float d0 = acc[n][0]*adv[0], d1 = acc[n][1]*adv[1];
        float d2 = acc[n][2]*adv[2], d3 = acc[n][3]*adv[3];
        for (int off = 32; off >= 1; off >>= 1){
            s0 += __shfl_xor(s0, off, 64); s1 += __shfl_xor(s1, off, 64);
            s2 += __shfl_xor(s2, off, 64); s3 += __shfl_xor(s3, off, 64);
            d0 += __shfl_xor(d0, off, 64); d1 += __shfl_xor(d1, off, 64);
            d2 += __shfl_xor(d2, off, 64); d3 += __shfl_xor(d3, off, 64);
        }
        if (lane == 0){
            *(float4*)&asrc[(size_t)node * 4] = make_float4(s0, s1, s2, s3);
            *(float4*)&adst[(size_t)node * 4] = make_float4(d0, d1, d2, d3);
        }
    }
}

// ============================ CSR build (once) ============================
__global__ void deg_init_kernel(int* __restrict__ deg, int N){
    int i = blockIdx.x * blockDim.x + threadIdx.x;
    if (i < N) deg[i] = 1;                        // self-loop
}

__global__ void deg_hist_kernel(const int* __restrict__ ei, int E, int* __restrict__ deg){
    int e = blockIdx.x * blockDim.x + threadIdx.x;
    if (e < E) atomicAdd(&deg[ei[E + e]], 1);
}

// ---- parallel scan: per-1024-block partial sums ----
__global__ __launch_bounds__(256) void part_sum_kernel(const int* __restrict__ deg,
                                                       int* __restrict__ bsum, int N)
{
    __shared__ int red[256];
    const int t = threadIdx.x;
    const int i0 = blockIdx.x * 1024 + t * 4;
    int s = 0;
    if (i0 + 3 < N){
        const int4 v = *(const int4*)&deg[i0];
        s = v.x + v.y + v.z + v.w;
    } else {
#pragma unroll
        for (int j = 0; j < 4; ++j) if (i0 + j < N) s += deg[i0 + j];
    }
    red[t] = s; __syncthreads();
    for (int off = 128; off >= 1; off >>= 1){
        if (t < off) red[t] += red[t + off];
        __syncthreads();
    }
    if (t == 0) bsum[blockIdx.x] = red[0];
}

// ---- scan the (<=256) block partials in-place to exclusive offsets ----
__global__ __launch_bounds__(256) void scan_part_kernel(int* __restrict__ bsum, int nb,
                                                        int* __restrict__ row, int N)
{
    __shared__ int sh[256];
    const int t = threadIdx.x;
    const int v = (t < nb) ? bsum[t] : 0;
    sh[t] = v; __syncthreads();
    for (int off = 1; off < 256; off <<= 1){
        int u = (t >= off) ? sh[t - off] : 0;
        __syncthreads();
        sh[t] += u;
        __syncthreads();
    }
    if (t < nb) bsum[t] = sh[t] - v;              // exclusive
    if (t == nb - 1) row[N] = sh[t];              // total = E + N
}

// ---- distribute: intra-block scan -> row/cursor ----
__global__ __launch_bounds__(256) void distribute_kernel(const int* __restrict__ deg,
    const int* __restrict__ bsum, int* __restrict__ row, int* __restrict__ cursor, int N)
{
    __shared__ int ts[256];
    const int t = threadIdx.x;
    const int i0 = blockIdx.x * 1024 + t * 4;
    int d[4]; int s = 0;
#pragma unroll
    for (int j = 0; j < 4; ++j){ d[j] = (i0 + j < N) ? deg[i0 + j] : 0; s += d[j]; }
    ts[t] = s; __syncthreads();
    for (int off = 1; off < 256; off <<= 1){
        int u = (t >= off) ? ts[t - off] : 0;
        __syncthreads();
        ts[t] += u;
        __syncthreads();
    }
    int base = bsum[blockIdx.x] + ts[t] - s;      // exclusive prefix for this thread
#pragma unroll
    for (int j = 0; j < 4; ++j){
        if (i0 + j < N){ row[i0 + j] = base; cursor[i0 + j] = base; base += d[j]; }
    }
}

__global__ void scatter_kernel(const int* __restrict__ ei, int E, int N,
                               int* __restrict__ cursor, int* __restrict__ csr)
{
    int e = blockIdx.x * blockDim.x + threadIdx.x;
    if (e >= E + N) return;
    int s, d;
    if (e < E){ s = ei[e]; d = ei[E + e]; } else { s = d = e - E; }
    int pos = atomicAdd(&cursor[d], 1);
    csr[pos] = s;
}

// =========================================================================
// Gather-aggregate per destination node: one wave per node. h is packed bf16.
// =========================================================================
__global__ __launch_bounds__(256) void agg4_kernel(
    const int* __restrict__ row, const int* __restrict__ csr,
    const float* __restrict__ asrc, const float* __restrict__ adst,
    const unsigned short* __restrict__ h,
    const float* __restrict__ b, const float* __restrict__ g,
    const float* __restrict__ be, const float* __restrict__ mean,
    const float* __restrict__ var,
    const float* __restrict__ res, float* __restrict__ outp, int N)
{
    const int wid = threadIdx.x >> 6, lane = threadIdx.x & 63;
    const int node = blockIdx.x * 4 + wid;
    if (node >= N) return;
    const int beg = row[node], end = row[node + 1];

    const float4 ad = *(const float4*)&adst[(size_t)node * 4];

    // ---- pass 1: per-head max, lane-parallel over edges ----
    float m0 = -1e30f, m1 = -1e30f, m2 = -1e30f, m3 = -1e30f;
    for (int i = beg + lane; i < end; i += 64){
        const int s = csr[i];
        const float4 as = *(const float4*)&asrc[(size_t)s * 4];
        float v0 = as.x + ad.x, v1 = as.y + ad.y, v2 = as.z + ad.z, v3 = as.w + ad.w;
        v0 = v0 > 0.f ? v0 : NEG_SLOPE * v0;
        v1 = v1 > 0.f ? v1 : NEG_SLOPE * v1;
        v2 = v2 > 0.f ? v2 : NEG_SLOPE * v2;
        v3 = v3 > 0.f ? v3 : NEG_SLOPE * v3;
        m0 = fmaxf(m0, v0); m1 = fmaxf(m1, v1);
        m2 = fmaxf(m2, v2); m3 = fmaxf(m3, v3);
    }
    for (int off = 32; off >= 1; off >>= 1){
        m0 = fmaxf(m0, __shfl_xor(m0, off, 64));
        m1 = fmaxf(m1, __shfl_xor(m1, off, 64));
        m2 = fmaxf(m2, __shfl_xor(m2, off, 64));
        m3 = fmaxf(m3, __shfl_xor(m3, off, 64));
    }

    // ---- pass 2: weighted gather-accumulate (2-unrolled for MLP) ----
    float a0 = 0.f, a1 = 0.f, a2 = 0.f, a3 = 0.f;
    float d0 = 0.f, d1 = 0.f, d2 = 0.f, d3 = 0.f;

#define EDGE_BODY(sv)                                                          \
    {                                                                          \
        const int s_ = (sv);                                                   \
        const float4 as_ = *(const float4*)&asrc[(size_t)s_ * 4];              \
        const ushort4 hv_ = *(const ushort4*)&h[(size_t)s_ * 256 + lane * 4];  \
        float v0_ = as_.x + ad.x, v1_ = as_.y + ad.y;                          \
        float v2_ = as_.z + ad.z, v3_ = as_.w + ad.w;                          \
        v0_ = v0_ > 0.f ? v0_ : NEG_SLOPE * v0_;                               \
        v1_ = v1_ > 0.f ? v1_ : NEG_SLOPE * v1_;                               \
        v2_ = v2_ > 0.f ? v2_ : NEG_SLOPE * v2_;                               \
        v3_ = v3_ > 0.f ? v3_ : NEG_SLOPE * v3_;                               \
        const float p0_ = __expf(v0_ - m0), p1_ = __expf(v1_ - m1);            \
        const float p2_ = __expf(v2_ - m2), p3_ = __expf(v3_ - m3);            \
        a0 = fmaf(p0_, bf2f(hv_.x), a0); a1 = fmaf(p1_, bf2f(hv_.y), a1);      \
        a2 = fmaf(p2_, bf2f(hv_.z), a2); a3 = fmaf(p3_, bf2f(hv_.w), a3);      \
        d0 += p0_; d1 += p1_; d2 += p2_; d3 += p3_;                            \
    }

    int i = beg;
    for (; i + 2 <= end; i += 2){
        const int sA = csr[i], sB = csr[i + 1];
        EDGE_BODY(sA);
        EDGE_BODY(sB);
    }
    for (; i < end; ++i) EDGE_BODY(csr[i]);
#undef EDGE_BODY

    // ---- fused epilogue ----
    float* o = &outp[(size_t)node * 256];
    const float vals[4] = { a0 / d0, a1 / d1, a2 / d2, a3 / d3 };
#pragma unroll
    for (int hd = 0; hd < 4; ++hd){
        const int c = hd * 64 + lane;
        float vv = vals[hd] + b[c];
        vv = (vv - mean[c]) * (g[c] * rsqrtf(var[c] + BN_EPS)) + be[c];
        vv = vv > 0.f ? vv : (__expf(vv) - 1.f);
        if (res) vv += res[(size_t)node * 256 + c];
        o[c] = vv;
    }
}

// ------------------------- layer 2 (heads=1, C=1) -------------------------
__global__ __launch_bounds__(256) void gemm2_kernel(
    const float* __restrict__ x, const float* __restrict__ W2,
    float* __restrict__ h2, int N)
{
    const int wid = threadIdx.x >> 6, lane = threadIdx.x & 63;
    const int n = blockIdx.x * 4 + wid;
    if (n >= N) return;
    float sum = 0.f;
#pragma unroll
    for (int i = 0; i < 4; ++i)
        sum += x[(size_t)n*256 + i*64 + lane] * W2[i*64 + lane];
    for (int off = 32; off >= 1; off >>= 1) sum += __shfl_xor(sum, off, 64);
    if (lane == 0) h2[n] = sum;
}

__global__ void agg2_kernel(const int* __restrict__ row, const int* __restrict__ csr,
                            const float* __restrict__ h2,
                            const float* __restrict__ as2, const float* __restrict__ ad2,
                            const float* __restrict__ b2, float* __restrict__ out, int N)
{
    const int n = blockIdx.x * blockDim.x + threadIdx.x;
    if (n >= N) return;
    const float A_s = as2[0];
    const float hd  = h2[n] * ad2[0];
    const int beg = row[n], end = row[n + 1];
    float m = -1e30f;
    for (int i = beg; i < end; ++i){
        float a = fmaf(A_s, h2[csr[i]], hd);
        a = a > 0.f ? a : NEG_SLOPE * a;
        m = fmaxf(m, a);
    }
    float den = 0.f, acc = 0.f;
    for (int i = beg; i < end; ++i){
        const float hv = h2[csr[i]];
        float a = fmaf(A_s, hv, hd);
        a = a > 0.f ? a : NEG_SLOPE * a;
        const float p = __expf(a - m);
        den += p; acc = fmaf(p, hv, acc);
    }
    out[n] = acc / den + b2[0];
}

// =========================================================================
extern "C" void kernel_launch(void* const* d_in, const int* in_sizes, int n_in,
                              void* d_out, int out_size, void* d_ws, size_t ws_size,
                              hipStream_t stream)
{
    const float* x   = (const float*)d_in[0];
    const int*   ei  = (const int*)  d_in[1];
    const float* W0  = (const float*)d_in[2];
    const float* as0 = (const float*)d_in[3];
    const float* ad0 = (const float*)d_in[4];
    const float* b0  = (const float*)d_in[5];
    const float* W1  = (const float*)d_in[6];
    const float* as1 = (const float*)d_in[7];
    const float* ad1 = (const float*)d_in[8];
    const float* b1  = (const float*)d_in[9];
    const float* W2  = (const float*)d_in[10];
    const float* as2 = (const float*)d_in[11];
    const float* ad2 = (const float*)d_in[12];
    const float* b2  = (const float*)d_in[13];
    const float* g0  = (const float*)d_in[14];
    const float* be0 = (const float*)d_in[15];
    const float* m0  = (const float*)d_in[16];
    const float* v0  = (const float*)d_in[17];
    const float* g1  = (const float*)d_in[18];
    const float* be1 = (const float*)d_in[19];
    const float* m1  = (const float*)d_in[20];
    const float* v1  = (const float*)d_in[21];

    const int N = in_sizes[0] / 128;
    const int E = in_sizes[1] / 2;
    const int EN = E + N;

    // ---- workspace layout ----
    char* w = (char*)d_ws;
    unsigned short* H = (unsigned short*)w;  w += (size_t)N * 256 * 2;  // bf16 packed h
    float*    P0     = (float*)w;   w += (size_t)N * 256 * 4;  // layer0 out (residual)
    float*    P1     = (float*)w;   w += (size_t)N * 256 * 4;  // layer1 out
    float*    asrc   = (float*)w;   w += (size_t)N * 4 * 4;
    float*    adst   = (float*)w;   w += (size_t)N * 4 * 4;
    int*      deg    = (int*)w;     w += (size_t)N * 4;
    int*      rowp   = (int*)w;     w += (size_t)(N + 1) * 4;
    int*      cursor = (int*)w;     w += (size_t)N * 4;
    int*      csr    = (int*)w;     w += (size_t)EN * 4;
    float*    h2     = (float*)w;   w += (size_t)N * 4;
    int*      bsum   = (int*)w;     w += 256 * 4;

    const int gN32  = (N + 31) / 32;
    const int gN4   = (N + 3) / 4;
    const int gNt   = (N + 255) / 256;
    const int gE    = (E + 255) / 256;
    const int gEN   = (EN + 255) / 256;
    const int nb    = (N + 1023) / 1024;          // scan blocks (<=256)

    // ---------------- CSR build (shared by all layers) ----------------
    deg_init_kernel<<<gNt, 256, 0, stream>>>(deg, N);
    deg_hist_kernel<<<gE, 256, 0, stream>>>(ei, E, deg);
    part_sum_kernel<<<nb, 256, 0, stream>>>(deg, bsum, N);
    scan_part_kernel<<<1, 256, 0, stream>>>(bsum, nb, rowp, N);
    distribute_kernel<<<nb, 256, 0, stream>>>(deg, bsum, rowp, cursor, N);
    scatter_kernel<<<gEN, 256, 0, stream>>>(ei, E, N, cursor, csr);

    // ---------------- layer 0 ----------------
    gemm_alpha_kernel<128><<<gN32, 256, 0, stream>>>(x, W0, as0, ad0, H, asrc, adst, N);
    agg4_kernel<<<gN4, 256, 0, stream>>>(rowp, csr, asrc, adst, H,
                                         b0, g0, be0, m0, v0, nullptr, P0, N);

    // ---------------- layer 1 ----------------
    gemm_alpha_kernel<256><<<gN32, 256, 0, stream>>>(P0, W1, as1, ad1, H, asrc, adst, N);
    agg4_kernel<<<gN4, 256, 0, stream>>>(rowp, csr, asrc, adst, H,
                                         b1, g1, be1, m1, v1, P0, P1, N);

    // ---------------- layer 2 ----------------
    gemm2_kernel<<<gN4, 256, 0, stream>>>(P1, W2, h2, N);
    agg2_kernel<<<gNt, 256, 0, stream>>>(rowp, csr, h2, as2, ad2, b2, (float*)d_out, N);
}

// Round 5
// 461.051 us; speedup vs baseline: 5.3573x; 1.1442x over previous
//
#include <hip/hip_runtime.h>
#include <math.h>

#define NEG_SLOPE 0.2f
#define BN_EPS 1e-5f

static __device__ __forceinline__ unsigned short f2bf(float f){
    unsigned u = __float_as_uint(f);
    u += 0x7FFFu + ((u >> 16) & 1u);          // round-to-nearest-even
    return (unsigned short)(u >> 16);
}
static __device__ __forceinline__ float bf2f(unsigned short v){
    return __uint_as_float((unsigned)v << 16);
}

// =========================================================================
// GEMM h = x @ W  ([N,K] @ [K,256]) + per-head alpha reductions.
// Block = 256 thr = 4 waves; 32-node x-tile staged in K-chunks of 128 cols
// (LDS = 16 KB -> 8 blocks/CU, thread-capped 100% static occupancy).
// Lane l owns channels {c*64+l, c=0..3} (one channel per head).
// h output written as packed bf16 [N][64][4] (channel-major, head-minor).
// =========================================================================
template<int K>
__global__ __launch_bounds__(256) void gemm_alpha_kernel(
    const float* __restrict__ x, const float* __restrict__ W,
    const float* __restrict__ a_s, const float* __restrict__ a_d,
    unsigned short* __restrict__ hout,
    float* __restrict__ asrc, float* __restrict__ adst, int N)
{
    constexpr int NB = 32;
    constexpr int KC = (K > 128) ? 128 : K;       // staged columns per chunk
    __shared__ float xs[NB * KC];
    const int t = threadIdx.x, lane = t & 63, wid = t >> 6;
    const int n0 = blockIdx.x * NB;

    float acc[8][4];
#pragma unroll
    for (int n = 0; n < 8; ++n)
#pragma unroll
        for (int c = 0; c < 4; ++c) acc[n][c] = 0.f;

    for (int k0 = 0; k0 < K; k0 += KC){
        __syncthreads();                          // previous chunk fully read
        for (int i = t; i < NB * KC / 4; i += 256){
            const int n  = i / (KC / 4);
            const int kk = (i % (KC / 4)) * 4;
            const int node = n0 + n;
            float4 v = make_float4(0.f, 0.f, 0.f, 0.f);
            if (node < N) v = *(const float4*)&x[(size_t)node * K + k0 + kk];
            *(float4*)&xs[n * KC + kk] = v;
        }
        __syncthreads();

        for (int k = 0; k < KC; k += 4){
            float w[4][4];
#pragma unroll
            for (int j = 0; j < 4; ++j)
#pragma unroll
                for (int c = 0; c < 4; ++c)
                    w[j][c] = W[(size_t)(k0 + k + j) * 256 + c * 64 + lane];
#pragma unroll
            for (int n = 0; n < 8; ++n){
                const float4 xv = *(const float4*)&xs[(wid * 8 + n) * KC + k];
#pragma unroll
                for (int c = 0; c < 4; ++c){
                    acc[n][c] = fmaf(xv.x, w[0][c], acc[n][c]);
                    acc[n][c] = fmaf(xv.y, w[1][c], acc[n][c]);
                    acc[n][c] = fmaf(xv.z, w[2][c], acc[n][c]);
                    acc[n][c] = fmaf(xv.w, w[3][c], acc[n][c]);
                }
            }
        }
    }

    float asv[4], adv[4];
#pragma unroll
    for (int c = 0; c < 4; ++c){
        asv[c] = a_s[c * 64 + lane];
        adv[c] = a_d[c * 64 + lane];
    }

    for (int n = 0; n < 8; ++n){
        const int node = n0 + wid * 8 + n;
        if (node >= N) break;                    // uniform across wave
        ushort4 hp;
        hp.x = f2bf(acc[n][0]); hp.y = f2bf(acc[n][1]);
        hp.z = f2bf(acc[n][2]); hp.w = f2bf(acc[n][3]);
        *(ushort4*)&hout[(size_t)node * 256 + lane * 4] = hp;

        float s0 = acc[n][0]*asv[0], s1 = acc[n][1]*asv[1];
        float s2 = acc[n][2]*asv[2], s3 = acc[n][3]*asv[3];
        float d0 = acc[n][0]*adv[0], d1 = acc[n][1]*adv[1];
        float d2 = acc[n][2]*adv[2], d3 = acc[n][3]*adv[3];
        for (int off = 32; off >= 1; off >>= 1){
            s0 += __shfl_xor(s0, off, 64); s1 += __shfl_xor(s1, off, 64);
            s2 += __shfl_xor(s2, off, 64); s3 += __shfl_xor(s3, off, 64);
            d0 += __shfl_xor(d0, off, 64); d1 += __shfl_xor(d1, off, 64);
            d2 += __shfl_xor(d2, off, 64); d3 += __shfl_xor(d3, off, 64);
        }
        if (lane == 0){
            *(float4*)&asrc[(size_t)node * 4] = make_float4(s0, s1, s2, s3);
            *(float4*)&adst[(size_t)node * 4] = make_float4(d0, d1, d2, d3);
        }
    }
}

// ============================ CSR build (once) ============================
__global__ void deg_init_kernel(int* __restrict__ deg, int N){
    int i = blockIdx.x * blockDim.x + threadIdx.x;
    if (i < N) deg[i] = 1;                        // self-loop
}

__global__ void deg_hist_kernel(const int* __restrict__ ei, int E, int* __restrict__ deg){
    int e = blockIdx.x * blockDim.x + threadIdx.x;
    if (e < E) atomicAdd(&deg[ei[E + e]], 1);
}

__global__ __launch_bounds__(256) void part_sum_kernel(const int* __restrict__ deg,
                                                       int* __restrict__ bsum, int N)
{
    __shared__ int red[256];
    const int t = threadIdx.x;
    const int i0 = blockIdx.x * 1024 + t * 4;
    int s = 0;
    if (i0 + 3 < N){
        const int4 v = *(const int4*)&deg[i0];
        s = v.x + v.y + v.z + v.w;
    } else {
#pragma unroll
        for (int j = 0; j < 4; ++j) if (i0 + j < N) s += deg[i0 + j];
    }
    red[t] = s; __syncthreads();
    for (int off = 128; off >= 1; off >>= 1){
        if (t < off) red[t] += red[t + off];
        __syncthreads();
    }
    if (t == 0) bsum[blockIdx.x] = red[0];
}

__global__ __launch_bounds__(256) void scan_part_kernel(int* __restrict__ bsum, int nb,
                                                        int* __restrict__ row, int N)
{
    __shared__ int sh[256];
    const int t = threadIdx.x;
    const int v = (t < nb) ? bsum[t] : 0;
    sh[t] = v; __syncthreads();
    for (int off = 1; off < 256; off <<= 1){
        int u = (t >= off) ? sh[t - off] : 0;
        __syncthreads();
        sh[t] += u;
        __syncthreads();
    }
    if (t < nb) bsum[t] = sh[t] - v;              // exclusive
    if (t == nb - 1) row[N] = sh[t];              // total = E + N
}

__global__ __launch_bounds__(256) void distribute_kernel(const int* __restrict__ deg,
    const int* __restrict__ bsum, int* __restrict__ row, int* __restrict__ cursor, int N)
{
    __shared__ int ts[256];
    const int t = threadIdx.x;
    const int i0 = blockIdx.x * 1024 + t * 4;
    int d[4]; int s = 0;
#pragma unroll
    for (int j = 0; j < 4; ++j){ d[j] = (i0 + j < N) ? deg[i0 + j] : 0; s += d[j]; }
    ts[t] = s; __syncthreads();
    for (int off = 1; off < 256; off <<= 1){
        int u = (t >= off) ? ts[t - off] : 0;
        __syncthreads();
        ts[t] += u;
        __syncthreads();
    }
    int base = bsum[blockIdx.x] + ts[t] - s;      // exclusive prefix for this thread
#pragma unroll
    for (int j = 0; j < 4; ++j){
        if (i0 + j < N){ row[i0 + j] = base; cursor[i0 + j] = base; base += d[j]; }
    }
}

__global__ void scatter_kernel(const int* __restrict__ ei, int E, int N,
                               int* __restrict__ cursor, int* __restrict__ csr)
{
    int e = blockIdx.x * blockDim.x + threadIdx.x;
    if (e >= E + N) return;
    int s, d;
    if (e < E){ s = ei[e]; d = ei[E + e]; } else { s = d = e - E; }
    int pos = atomicAdd(&cursor[d], 1);
    csr[pos] = s;
}

// =========================================================================
// Gather-aggregate per destination node: one wave per node, 4 waves/block.
// No segment-max (logits are O(10); exp is safe in fp32; softmax is
// shift-invariant). Phase A: lane-parallel p = exp(leakyrelu(e)) -> LDS,
// denom via butterfly. Phase B: serial h-gather weighted accumulate.
// Fused epilogue: /denom + bias + BN(eval) + ELU (+ residual).
// =========================================================================
#define DEG_CAP 128
__global__ __launch_bounds__(256) void agg4_kernel(
    const int* __restrict__ row, const int* __restrict__ csr,
    const float* __restrict__ asrc, const float* __restrict__ adst,
    const unsigned short* __restrict__ h,
    const float* __restrict__ b, const float* __restrict__ g,
    const float* __restrict__ be, const float* __restrict__ mean,
    const float* __restrict__ var,
    const float* __restrict__ res, float* __restrict__ outp, int N)
{
    __shared__ float4 plds[4][DEG_CAP];
    __shared__ int    slds[4][DEG_CAP];
    const int wid = threadIdx.x >> 6, lane = threadIdx.x & 63;
    const int node = blockIdx.x * 4 + wid;
    if (node >= N) return;
    const int beg = row[node], end = row[node + 1];

    const float4 ad = *(const float4*)&adst[(size_t)node * 4];

    // ---- phase A: lane-parallel edge weights + denom ----
    float d0 = 0.f, d1 = 0.f, d2 = 0.f, d3 = 0.f;
    for (int i = beg + lane; i < end; i += 64){
        const int s = csr[i];
        const float4 as = *(const float4*)&asrc[(size_t)s * 4];
        float v0 = as.x + ad.x, v1 = as.y + ad.y, v2 = as.z + ad.z, v3 = as.w + ad.w;
        v0 = v0 > 0.f ? v0 : NEG_SLOPE * v0;
        v1 = v1 > 0.f ? v1 : NEG_SLOPE * v1;
        v2 = v2 > 0.f ? v2 : NEG_SLOPE * v2;
        v3 = v3 > 0.f ? v3 : NEG_SLOPE * v3;
        const float p0 = __expf(v0), p1 = __expf(v1);
        const float p2 = __expf(v2), p3 = __expf(v3);
        d0 += p0; d1 += p1; d2 += p2; d3 += p3;
        const int slot = i - beg;
        if (slot < DEG_CAP){
            plds[wid][slot] = make_float4(p0, p1, p2, p3);
            slds[wid][slot] = s;
        }
    }
    for (int off = 32; off >= 1; off >>= 1){
        d0 += __shfl_xor(d0, off, 64); d1 += __shfl_xor(d1, off, 64);
        d2 += __shfl_xor(d2, off, 64); d3 += __shfl_xor(d3, off, 64);
    }

    // ---- phase B: serial weighted gather-accumulate ----
    float a0 = 0.f, a1 = 0.f, a2 = 0.f, a3 = 0.f;
    const int deg = end - beg;
    const int degc = deg < DEG_CAP ? deg : DEG_CAP;

#define EDGE_BODY(slot)                                                        \
    {                                                                          \
        const float4 p_ = plds[wid][slot];                                     \
        const int s_ = slds[wid][slot];                                        \
        const ushort4 hv_ = *(const ushort4*)&h[(size_t)s_ * 256 + lane * 4];  \
        a0 = fmaf(p_.x, bf2f(hv_.x), a0); a1 = fmaf(p_.y, bf2f(hv_.y), a1);    \
        a2 = fmaf(p_.z, bf2f(hv_.z), a2); a3 = fmaf(p_.w, bf2f(hv_.w), a3);    \
    }

    int i = 0;
    for (; i + 2 <= degc; i += 2){
        EDGE_BODY(i);
        EDGE_BODY(i + 1);
    }
    for (; i < degc; ++i) EDGE_BODY(i);
#undef EDGE_BODY

    // overflow path (deg > DEG_CAP): recompute p inline (statistically never)
    for (int j = beg + DEG_CAP; j < end; ++j){
        const int s = csr[j];
        const float4 as = *(const float4*)&asrc[(size_t)s * 4];
        float v0 = as.x + ad.x, v1 = as.y + ad.y, v2 = as.z + ad.z, v3 = as.w + ad.w;
        v0 = v0 > 0.f ? v0 : NEG_SLOPE * v0;
        v1 = v1 > 0.f ? v1 : NEG_SLOPE * v1;
        v2 = v2 > 0.f ? v2 : NEG_SLOPE * v2;
        v3 = v3 > 0.f ? v3 : NEG_SLOPE * v3;
        const ushort4 hv = *(const ushort4*)&h[(size_t)s * 256 + lane * 4];
        a0 = fmaf(__expf(v0), bf2f(hv.x), a0); a1 = fmaf(__expf(v1), bf2f(hv.y), a1);
        a2 = fmaf(__expf(v2), bf2f(hv.z), a2); a3 = fmaf(__expf(v3), bf2f(hv.w), a3);
    }

    // ---- fused epilogue ----
    float* o = &outp[(size_t)node * 256];
    const float vals[4] = { a0 / d0, a1 / d1, a2 / d2, a3 / d3 };
#pragma unroll
    for (int hd = 0; hd < 4; ++hd){
        const int c = hd * 64 + lane;
        float vv = vals[hd] + b[c];
        vv = (vv - mean[c]) * (g[c] * rsqrtf(var[c] + BN_EPS)) + be[c];
        vv = vv > 0.f ? vv : (__expf(vv) - 1.f);
        if (res) vv += res[(size_t)node * 256 + c];
        o[c] = vv;
    }
}

// ------------------------- layer 2 (heads=1, C=1) -------------------------
__global__ __launch_bounds__(256) void gemm2_kernel(
    const float* __restrict__ x, const float* __restrict__ W2,
    float* __restrict__ h2, int N)
{
    const int wid = threadIdx.x >> 6, lane = threadIdx.x & 63;
    const int n = blockIdx.x * 4 + wid;
    if (n >= N) return;
    float sum = 0.f;
#pragma unroll
    for (int i = 0; i < 4; ++i)
        sum += x[(size_t)n*256 + i*64 + lane] * W2[i*64 + lane];
    for (int off = 32; off >= 1; off >>= 1) sum += __shfl_xor(sum, off, 64);
    if (lane == 0) h2[n] = sum;
}

__global__ void agg2_kernel(const int* __restrict__ row, const int* __restrict__ csr,
                            const float* __restrict__ h2,
                            const float* __restrict__ as2, const float* __restrict__ ad2,
                            const float* __restrict__ b2, float* __restrict__ out, int N)
{
    const int n = blockIdx.x * blockDim.x + threadIdx.x;
    if (n >= N) return;
    const float A_s = as2[0];
    const float hd  = h2[n] * ad2[0];
    const int beg = row[n], end = row[n + 1];
    float den = 0.f, acc = 0.f;
    for (int i = beg; i < end; ++i){
        const float hv = h2[csr[i]];
        float a = fmaf(A_s, hv, hd);
        a = a > 0.f ? a : NEG_SLOPE * a;
        const float p = __expf(a);
        den += p; acc = fmaf(p, hv, acc);
    }
    out[n] = acc / den + b2[0];
}

// =========================================================================
extern "C" void kernel_launch(void* const* d_in, const int* in_sizes, int n_in,
                              void* d_out, int out_size, void* d_ws, size_t ws_size,
                              hipStream_t stream)
{
    const float* x   = (const float*)d_in[0];
    const int*   ei  = (const int*)  d_in[1];
    const float* W0  = (const float*)d_in[2];
    const float* as0 = (const float*)d_in[3];
    const float* ad0 = (const float*)d_in[4];
    const float* b0  = (const float*)d_in[5];
    const float* W1  = (const float*)d_in[6];
    const float* as1 = (const float*)d_in[7];
    const float* ad1 = (const float*)d_in[8];
    const float* b1  = (const float*)d_in[9];
    const float* W2  = (const float*)d_in[10];
    const float* as2 = (const float*)d_in[11];
    const float* ad2 = (const float*)d_in[12];
    const float* b2  = (const float*)d_in[13];
    const float* g0  = (const float*)d_in[14];
    const float* be0 = (const float*)d_in[15];
    const float* m0  = (const float*)d_in[16];
    const float* v0  = (const float*)d_in[17];
    const float* g1  = (const float*)d_in[18];
    const float* be1 = (const float*)d_in[19];
    const float* m1  = (const float*)d_in[20];
    const float* v1  = (const float*)d_in[21];

    const int N = in_sizes[0] / 128;
    const int E = in_sizes[1] / 2;
    const int EN = E + N;

    // ---- workspace layout ----
    char* w = (char*)d_ws;
    unsigned short* H = (unsigned short*)w;  w += (size_t)N * 256 * 2;  // bf16 packed h
    float*    P0     = (float*)w;   w += (size_t)N * 256 * 4;  // layer0 out (residual)
    float*    P1     = (float*)w;   w += (size_t)N * 256 * 4;  // layer1 out
    float*    asrc   = (float*)w;   w += (size_t)N * 4 * 4;
    float*    adst   = (float*)w;   w += (size_t)N * 4 * 4;
    int*      deg    = (int*)w;     w += (size_t)N * 4;
    int*      rowp   = (int*)w;     w += (size_t)(N + 1) * 4;
    int*      cursor = (int*)w;     w += (size_t)N * 4;
    int*      csr    = (int*)w;     w += (size_t)EN * 4;
    float*    h2     = (float*)w;   w += (size_t)N * 4;
    int*      bsum   = (int*)w;     w += 256 * 4;

    const int gN32  = (N + 31) / 32;
    const int gN4   = (N + 3) / 4;
    const int gNt   = (N + 255) / 256;
    const int gE    = (E + 255) / 256;
    const int gEN   = (EN + 255) / 256;
    const int nb    = (N + 1023) / 1024;          // scan blocks (<=256)

    // ---------------- CSR build (shared by all layers) ----------------
    deg_init_kernel<<<gNt, 256, 0, stream>>>(deg, N);
    deg_hist_kernel<<<gE, 256, 0, stream>>>(ei, E, deg);
    part_sum_kernel<<<nb, 256, 0, stream>>>(deg, bsum, N);
    scan_part_kernel<<<1, 256, 0, stream>>>(bsum, nb, rowp, N);
    distribute_kernel<<<nb, 256, 0, stream>>>(deg, bsum, rowp, cursor, N);
    scatter_kernel<<<gEN, 256, 0, stream>>>(ei, E, N, cursor, csr);

    // ---------------- layer 0 ----------------
    gemm_alpha_kernel<128><<<gN32, 256, 0, stream>>>(x, W0, as0, ad0, H, asrc, adst, N);
    agg4_kernel<<<gN4, 256, 0, stream>>>(rowp, csr, asrc, adst, H,
                                         b0, g0, be0, m0, v0, nullptr, P0, N);

    // ---------------- layer 1 ----------------
    gemm_alpha_kernel<256><<<gN32, 256, 0, stream>>>(P0, W1, as1, ad1, H, asrc, adst, N);
    agg4_kernel<<<gN4, 256, 0, stream>>>(rowp, csr, asrc, adst, H,
                                         b1, g1, be1, m1, v1, P0, P1, N);

    // ---------------- layer 2 ----------------
    gemm2_kernel<<<gN4, 256, 0, stream>>>(P1, W2, h2, N);
    agg2_kernel<<<gNt, 256, 0, stream>>>(rowp, csr, h2, as2, ad2, b2, (float*)d_out, N);
}

// Round 6
// 451.185 us; speedup vs baseline: 5.4745x; 1.0219x over previous
//
#include <hip/hip_runtime.h>
#include <math.h>

#define NEG_SLOPE 0.2f
#define BN_EPS 1e-5f

static __device__ __forceinline__ unsigned short f2bf(float f){
    unsigned u = __float_as_uint(f);
    u += 0x7FFFu + ((u >> 16) & 1u);          // round-to-nearest-even
    return (unsigned short)(u >> 16);
}
static __device__ __forceinline__ float bf2f(unsigned short v){
    return __uint_as_float((unsigned)v << 16);
}

// async global->LDS, 16B per lane; LDS dest is wave-uniform base + lane*16
static __device__ __forceinline__ void gload_lds16(const float* g, float* l){
    __builtin_amdgcn_global_load_lds(
        (const __attribute__((address_space(1))) void*)g,
        (__attribute__((address_space(3))) void*)l, 16, 0, 0);
}

// ---- repack W[k][c*64+lane] -> Wp[k][lane*4+c] (float4-loadable per thread) ----
__global__ void repack_kernel(const float* __restrict__ W, float* __restrict__ Wp, int total){
    int i = blockIdx.x * 256 + threadIdx.x;
    if (i >= total) return;
    const int k = i >> 8, r = i & 255;
    const int lane = r >> 2, c = r & 3;
    Wp[i] = W[(k << 8) + c * 64 + lane];
}

// =========================================================================
// GEMM h = x @ W  ([N,K] @ [K,256]) + per-head alpha reductions.
// Block = 256 thr = 4 waves; 32-node x-tile staged in K-chunks of 128 cols
// via global_load_lds (16 KB LDS). Lane l owns channels {c*64+l, c=0..3}.
// W pre-repacked so each (k, thread) reads one float4.
// h output written as packed bf16 [N][64][4] (channel-major, head-minor).
// =========================================================================
template<int K>
__global__ __launch_bounds__(256) void gemm_alpha_kernel(
    const float* __restrict__ x, const float* __restrict__ Wp,
    const float* __restrict__ a_s, const float* __restrict__ a_d,
    unsigned short* __restrict__ hout,
    float* __restrict__ asrc, float* __restrict__ adst, int N)
{
    constexpr int NB = 32;
    constexpr int KC = (K > 128) ? 128 : K;       // staged columns per chunk
    constexpr int F4 = KC / 4;                    // float4s per row-chunk
    __shared__ float xs[NB * KC];
    const int t = threadIdx.x, lane = t & 63, wid = t >> 6;
    const int n0 = blockIdx.x * NB;

    float acc[8][4];
#pragma unroll
    for (int n = 0; n < 8; ++n)
#pragma unroll
        for (int c = 0; c < 4; ++c) acc[n][c] = 0.f;

    for (int k0 = 0; k0 < K; k0 += KC){
        __syncthreads();                          // previous chunk fully read
#pragma unroll
        for (int r = 0; r < 4; ++r){              // NB*F4 / 256 == 4
            const int f0 = r * 256 + wid * 64;    // wave-uniform f4 slot base
            const int f  = f0 + lane;
            int node = n0 + f / F4;
            if (node > N - 1) node = N - 1;       // clamp; garbage discarded later
            const int kk = (f % F4) * 4;
            gload_lds16(&x[(size_t)node * K + k0 + kk], &xs[f0 * 4]);
        }
        __syncthreads();                          // drains vmcnt (incl. lds loads)

        for (int k = 0; k < KC; k += 4){
            float w[4][4];
#pragma unroll
            for (int j = 0; j < 4; ++j)
                *(float4*)&w[j][0] =
                    *(const float4*)&Wp[(size_t)(k0 + k + j) * 256 + (lane << 2)];
#pragma unroll
            for (int n = 0; n < 8; ++n){
                const float4 xv = *(const float4*)&xs[(wid * 8 + n) * KC + k];
#pragma unroll
                for (int c = 0; c < 4; ++c){
                    acc[n][c] = fmaf(xv.x, w[0][c], acc[n][c]);
                    acc[n][c] = fmaf(xv.y, w[1][c], acc[n][c]);
                    acc[n][c] = fmaf(xv.z, w[2][c], acc[n][c]);
                    acc[n][c] = fmaf(xv.w, w[3][c], acc[n][c]);
                }
            }
        }
    }

    float asv[4], adv[4];
#pragma unroll
    for (int c = 0; c < 4; ++c){
        asv[c] = a_s[c * 64 + lane];
        adv[c] = a_d[c * 64 + lane];
    }

    for (int n = 0; n < 8; ++n){
        const int node = n0 + wid * 8 + n;
        if (node >= N) break;                    // uniform across wave
        ushort4 hp;
        hp.x = f2bf(acc[n][0]); hp.y = f2bf(acc[n][1]);
        hp.z = f2bf(acc[n][2]); hp.w = f2bf(acc[n][3]);
        *(ushort4*)&hout[(size_t)node * 256 + lane * 4] = hp;

        float s0 = acc[n][0]*asv[0], s1 = acc[n][1]*asv[1];
        float s2 = acc[n][2]*asv[2], s3 = acc[n][3]*asv[3];
        float d0 = acc[n][0]*adv[0], d1 = acc[n][1]*adv[1];
        float d2 = acc[n][2]*adv[2], d3 = acc[n][3]*adv[3];
        for (int off = 32; off >= 1; off >>= 1){
            s0 += __shfl_xor(s0, off, 64); s1 += __shfl_xor(s1, off, 64);
            s2 += __shfl_xor(s2, off, 64); s3 += __shfl_xor(s3, off, 64);
            d0 += __shfl_xor(d0, off, 64); d1 += __shfl_xor(d1, off, 64);
            d2 += __shfl_xor(d2, off, 64); d3 += __shfl_xor(d3, off, 64);
        }
        if (lane == 0){
            *(float4*)&asrc[(size_t)node * 4] = make_float4(s0, s1, s2, s3);
            *(float4*)&adst[(size_t)node * 4] = make_float4(d0, d1, d2, d3);
        }
    }
}

// ============================ CSR build (once) ============================
__global__ void deg_init_kernel(int* __restrict__ deg, int N){
    int i = blockIdx.x * blockDim.x + threadIdx.x;
    if (i < N) deg[i] = 1;                        // self-loop
}

__global__ void deg_hist_kernel(const int* __restrict__ ei, int E, int* __restrict__ deg){
    int e = blockIdx.x * blockDim.x + threadIdx.x;
    if (e < E) atomicAdd(&deg[ei[E + e]], 1);
}

__global__ __launch_bounds__(256) void part_sum_kernel(const int* __restrict__ deg,
                                                       int* __restrict__ bsum, int N)
{
    __shared__ int red[256];
    const int t = threadIdx.x;
    const int i0 = blockIdx.x * 1024 + t * 4;
    int s = 0;
    if (i0 + 3 < N){
        const int4 v = *(const int4*)&deg[i0];
        s = v.x + v.y + v.z + v.w;
    } else {
#pragma unroll
        for (int j = 0; j < 4; ++j) if (i0 + j < N) s += deg[i0 + j];
    }
    red[t] = s; __syncthreads();
    for (int off = 128; off >= 1; off >>= 1){
        if (t < off) red[t] += red[t + off];
        __syncthreads();
    }
    if (t == 0) bsum[blockIdx.x] = red[0];
}

__global__ __launch_bounds__(256) void scan_part_kernel(int* __restrict__ bsum, int nb,
                                                        int* __restrict__ row, int N)
{
    __shared__ int sh[256];
    const int t = threadIdx.x;
    const int v = (t < nb) ? bsum[t] : 0;
    sh[t] = v; __syncthreads();
    for (int off = 1; off < 256; off <<= 1){
        int u = (t >= off) ? sh[t - off] : 0;
        __syncthreads();
        sh[t] += u;
        __syncthreads();
    }
    if (t < nb) bsum[t] = sh[t] - v;              // exclusive
    if (t == nb - 1) row[N] = sh[t];              // total = E + N
}

__global__ __launch_bounds__(256) void distribute_kernel(const int* __restrict__ deg,
    const int* __restrict__ bsum, int* __restrict__ row, int* __restrict__ cursor, int N)
{
    __shared__ int ts[256];
    const int t = threadIdx.x;
    const int i0 = blockIdx.x * 1024 + t * 4;
    int d[4]; int s = 0;
#pragma unroll
    for (int j = 0; j < 4; ++j){ d[j] = (i0 + j < N) ? deg[i0 + j] : 0; s += d[j]; }
    ts[t] = s; __syncthreads();
    for (int off = 1; off < 256; off <<= 1){
        int u = (t >= off) ? ts[t - off] : 0;
        __syncthreads();
        ts[t] += u;
        __syncthreads();
    }
    int base = bsum[blockIdx.x] + ts[t] - s;      // exclusive prefix for this thread
#pragma unroll
    for (int j = 0; j < 4; ++j){
        if (i0 + j < N){ row[i0 + j] = base; cursor[i0 + j] = base; base += d[j]; }
    }
}

__global__ void scatter_kernel(const int* __restrict__ ei, int E, int N,
                               int* __restrict__ cursor, int* __restrict__ csr)
{
    int e = blockIdx.x * blockDim.x + threadIdx.x;
    if (e >= E + N) return;
    int s, d;
    if (e < E){ s = ei[e]; d = ei[E + e]; } else { s = d = e - E; }
    int pos = atomicAdd(&cursor[d], 1);
    csr[pos] = s;
}

// =========================================================================
// Gather-aggregate per destination node: one wave per node, 4 waves/block.
// No segment-max (softmax shift-invariant; logits O(10), exp safe in fp32).
// =========================================================================
#define DEG_CAP 128
__global__ __launch_bounds__(256) void agg4_kernel(
    const int* __restrict__ row, const int* __restrict__ csr,
    const float* __restrict__ asrc, const float* __restrict__ adst,
    const unsigned short* __restrict__ h,
    const float* __restrict__ b, const float* __restrict__ g,
    const float* __restrict__ be, const float* __restrict__ mean,
    const float* __restrict__ var,
    const float* __restrict__ res, float* __restrict__ outp, int N)
{
    __shared__ float4 plds[4][DEG_CAP];
    __shared__ int    slds[4][DEG_CAP];
    const int wid = threadIdx.x >> 6, lane = threadIdx.x & 63;
    const int node = blockIdx.x * 4 + wid;
    if (node >= N) return;
    const int beg = row[node], end = row[node + 1];

    const float4 ad = *(const float4*)&adst[(size_t)node * 4];

    // ---- phase A: lane-parallel edge weights + denom ----
    float d0 = 0.f, d1 = 0.f, d2 = 0.f, d3 = 0.f;
    for (int i = beg + lane; i < end; i += 64){
        const int s = csr[i];
        const float4 as = *(const float4*)&asrc[(size_t)s * 4];
        float v0 = as.x + ad.x, v1 = as.y + ad.y, v2 = as.z + ad.z, v3 = as.w + ad.w;
        v0 = v0 > 0.f ? v0 : NEG_SLOPE * v0;
        v1 = v1 > 0.f ? v1 : NEG_SLOPE * v1;
        v2 = v2 > 0.f ? v2 : NEG_SLOPE * v2;
        v3 = v3 > 0.f ? v3 : NEG_SLOPE * v3;
        const float p0 = __expf(v0), p1 = __expf(v1);
        const float p2 = __expf(v2), p3 = __expf(v3);
        d0 += p0; d1 += p1; d2 += p2; d3 += p3;
        const int slot = i - beg;
        if (slot < DEG_CAP){
            plds[wid][slot] = make_float4(p0, p1, p2, p3);
            slds[wid][slot] = s;
        }
    }
    for (int off = 32; off >= 1; off >>= 1){
        d0 += __shfl_xor(d0, off, 64); d1 += __shfl_xor(d1, off, 64);
        d2 += __shfl_xor(d2, off, 64); d3 += __shfl_xor(d3, off, 64);
    }

    // ---- phase B: serial weighted gather-accumulate ----
    float a0 = 0.f, a1 = 0.f, a2 = 0.f, a3 = 0.f;
    const int deg = end - beg;
    const int degc = deg < DEG_CAP ? deg : DEG_CAP;

#define EDGE_BODY(slot)                                                        \
    {                                                                          \
        const float4 p_ = plds[wid][slot];                                     \
        const int s_ = slds[wid][slot];                                        \
        const ushort4 hv_ = *(const ushort4*)&h[(size_t)s_ * 256 + lane * 4];  \
        a0 = fmaf(p_.x, bf2f(hv_.x), a0); a1 = fmaf(p_.y, bf2f(hv_.y), a1);    \
        a2 = fmaf(p_.z, bf2f(hv_.z), a2); a3 = fmaf(p_.w, bf2f(hv_.w), a3);    \
    }

    int i = 0;
    for (; i + 2 <= degc; i += 2){
        EDGE_BODY(i);
        EDGE_BODY(i + 1);
    }
    for (; i < degc; ++i) EDGE_BODY(i);
#undef EDGE_BODY

    // overflow path (deg > DEG_CAP): recompute p inline (statistically never)
    for (int j = beg + DEG_CAP; j < end; ++j){
        const int s = csr[j];
        const float4 as = *(const float4*)&asrc[(size_t)s * 4];
        float v0 = as.x + ad.x, v1 = as.y + ad.y, v2 = as.z + ad.z, v3 = as.w + ad.w;
        v0 = v0 > 0.f ? v0 : NEG_SLOPE * v0;
        v1 = v1 > 0.f ? v1 : NEG_SLOPE * v1;
        v2 = v2 > 0.f ? v2 : NEG_SLOPE * v2;
        v3 = v3 > 0.f ? v3 : NEG_SLOPE * v3;
        const ushort4 hv = *(const ushort4*)&h[(size_t)s * 256 + lane * 4];
        a0 = fmaf(__expf(v0), bf2f(hv.x), a0); a1 = fmaf(__expf(v1), bf2f(hv.y), a1);
        a2 = fmaf(__expf(v2), bf2f(hv.z), a2); a3 = fmaf(__expf(v3), bf2f(hv.w), a3);
    }

    // ---- fused epilogue ----
    float* o = &outp[(size_t)node * 256];
    const float vals[4] = { a0 / d0, a1 / d1, a2 / d2, a3 / d3 };
#pragma unroll
    for (int hd = 0; hd < 4; ++hd){
        const int c = hd * 64 + lane;
        float vv = vals[hd] + b[c];
        vv = (vv - mean[c]) * (g[c] * rsqrtf(var[c] + BN_EPS)) + be[c];
        vv = vv > 0.f ? vv : (__expf(vv) - 1.f);
        if (res) vv += res[(size_t)node * 256 + c];
        o[c] = vv;
    }
}

// ------------------------- layer 2 (heads=1, C=1) -------------------------
__global__ __launch_bounds__(256) void gemm2_kernel(
    const float* __restrict__ x, const float* __restrict__ W2,
    float* __restrict__ h2, int N)
{
    const int wid = threadIdx.x >> 6, lane = threadIdx.x & 63;
    const int n = blockIdx.x * 4 + wid;
    if (n >= N) return;
    float sum = 0.f;
#pragma unroll
    for (int i = 0; i < 4; ++i)
        sum += x[(size_t)n*256 + i*64 + lane] * W2[i*64 + lane];
    for (int off = 32; off >= 1; off >>= 1) sum += __shfl_xor(sum, off, 64);
    if (lane == 0) h2[n] = sum;
}

__global__ void agg2_kernel(const int* __restrict__ row, const int* __restrict__ csr,
                            const float* __restrict__ h2,
                            const float* __restrict__ as2, const float* __restrict__ ad2,
                            const float* __restrict__ b2, float* __restrict__ out, int N)
{
    const int n = blockIdx.x * blockDim.x + threadIdx.x;
    if (n >= N) return;
    const float A_s = as2[0];
    const float hd  = h2[n] * ad2[0];
    const int beg = row[n], end = row[n + 1];
    float den = 0.f, acc = 0.f;
    for (int i = beg; i < end; ++i){
        const float hv = h2[csr[i]];
        float a = fmaf(A_s, hv, hd);
        a = a > 0.f ? a : NEG_SLOPE * a;
        const float p = __expf(a);
        den += p; acc = fmaf(p, hv, acc);
    }
    out[n] = acc / den + b2[0];
}

// =========================================================================
extern "C" void kernel_launch(void* const* d_in, const int* in_sizes, int n_in,
                              void* d_out, int out_size, void* d_ws, size_t ws_size,
                              hipStream_t stream)
{
    const float* x   = (const float*)d_in[0];
    const int*   ei  = (const int*)  d_in[1];
    const float* W0  = (const float*)d_in[2];
    const float* as0 = (const float*)d_in[3];
    const float* ad0 = (const float*)d_in[4];
    const float* b0  = (const float*)d_in[5];
    const float* W1  = (const float*)d_in[6];
    const float* as1 = (const float*)d_in[7];
    const float* ad1 = (const float*)d_in[8];
    const float* b1  = (const float*)d_in[9];
    const float* W2  = (const float*)d_in[10];
    const float* as2 = (const float*)d_in[11];
    const float* ad2 = (const float*)d_in[12];
    const float* b2  = (const float*)d_in[13];
    const float* g0  = (const float*)d_in[14];
    const float* be0 = (const float*)d_in[15];
    const float* m0  = (const float*)d_in[16];
    const float* v0  = (const float*)d_in[17];
    const float* g1  = (const float*)d_in[18];
    const float* be1 = (const float*)d_in[19];
    const float* m1  = (const float*)d_in[20];
    const float* v1  = (const float*)d_in[21];

    const int N = in_sizes[0] / 128;
    const int E = in_sizes[1] / 2;
    const int EN = E + N;

    // ---- workspace layout ----
    char* w = (char*)d_ws;
    unsigned short* H = (unsigned short*)w;  w += (size_t)N * 256 * 2;  // bf16 packed h
    float*    P0     = (float*)w;   w += (size_t)N * 256 * 4;  // layer0 out (residual)
    float*    P1     = (float*)w;   w += (size_t)N * 256 * 4;  // layer1 out
    float*    asrc   = (float*)w;   w += (size_t)N * 4 * 4;
    float*    adst   = (float*)w;   w += (size_t)N * 4 * 4;
    int*      deg    = (int*)w;     w += (size_t)N * 4;
    int*      rowp   = (int*)w;     w += (size_t)(N + 1) * 4;
    int*      cursor = (int*)w;     w += (size_t)N * 4;
    int*      csr    = (int*)w;     w += (size_t)EN * 4;
    float*    h2     = (float*)w;   w += (size_t)N * 4;
    int*      bsum   = (int*)w;     w += 256 * 4;
    float*    Wp0    = (float*)w;   w += (size_t)128 * 256 * 4;
    float*    Wp1    = (float*)w;   w += (size_t)256 * 256 * 4;

    const int gN32  = (N + 31) / 32;
    const int gN4   = (N + 3) / 4;
    const int gNt   = (N + 255) / 256;
    const int gE    = (E + 255) / 256;
    const int gEN   = (EN + 255) / 256;
    const int nb    = (N + 1023) / 1024;          // scan blocks (<=256)

    // ---------------- weight repack + CSR build ----------------
    repack_kernel<<<(128 * 256) / 256, 256, 0, stream>>>(W0, Wp0, 128 * 256);
    repack_kernel<<<(256 * 256) / 256, 256, 0, stream>>>(W1, Wp1, 256 * 256);
    deg_init_kernel<<<gNt, 256, 0, stream>>>(deg, N);
    deg_hist_kernel<<<gE, 256, 0, stream>>>(ei, E, deg);
    part_sum_kernel<<<nb, 256, 0, stream>>>(deg, bsum, N);
    scan_part_kernel<<<1, 256, 0, stream>>>(bsum, nb, rowp, N);
    distribute_kernel<<<nb, 256, 0, stream>>>(deg, bsum, rowp, cursor, N);
    scatter_kernel<<<gEN, 256, 0, stream>>>(ei, E, N, cursor, csr);

    // ---------------- layer 0 ----------------
    gemm_alpha_kernel<128><<<gN32, 256, 0, stream>>>(x, Wp0, as0, ad0, H, asrc, adst, N);
    agg4_kernel<<<gN4, 256, 0, stream>>>(rowp, csr, asrc, adst, H,
                                         b0, g0, be0, m0, v0, nullptr, P0, N);

    // ---------------- layer 1 ----------------
    gemm_alpha_kernel<256><<<gN32, 256, 0, stream>>>(P0, Wp1, as1, ad1, H, asrc, adst, N);
    agg4_kernel<<<gN4, 256, 0, stream>>>(rowp, csr, asrc, adst, H,
                                         b1, g1, be1, m1, v1, P0, P1, N);

    // ---------------- layer 2 ----------------
    gemm2_kernel<<<gN4, 256, 0, stream>>>(P1, W2, h2, N);
    agg2_kernel<<<gNt, 256, 0, stream>>>(rowp, csr, h2, as2, ad2, b2, (float*)d_out, N);
}

// Round 7
// 339.531 us; speedup vs baseline: 7.2748x; 1.3288x over previous
//
#include <hip/hip_runtime.h>
#include <math.h>

#define NEG_SLOPE 0.2f
#define BN_EPS 1e-5f

typedef __attribute__((ext_vector_type(8))) short bf16x8;
typedef __attribute__((ext_vector_type(4))) float f32x4;

static __device__ __forceinline__ unsigned short f2bf(float f){
    unsigned u = __float_as_uint(f);
    u += 0x7FFFu + ((u >> 16) & 1u);          // round-to-nearest-even
    return (unsigned short)(u >> 16);
}
static __device__ __forceinline__ float bf2f(unsigned short v){
    return __uint_as_float((unsigned)v << 16);
}

// async global->LDS, 16B/lane; LDS dest wave-uniform base + lane*16
static __device__ __forceinline__ void gload_lds16(const void* g, void* l){
    __builtin_amdgcn_global_load_lds(
        (const __attribute__((address_space(1))) void*)g,
        (__attribute__((address_space(3))) void*)l, 16, 0, 0);
}

// ---- fp32 -> (hi, lo) bf16 planes, elementwise ----
__global__ void conv_hilo_kernel(const float* __restrict__ x,
                                 unsigned short* __restrict__ hi,
                                 unsigned short* __restrict__ lo, int n4)
{
    int i = blockIdx.x * 256 + threadIdx.x;
    if (i >= n4) return;
    const float4 v = ((const float4*)x)[i];
    ushort4 h4, l4;
    h4.x = f2bf(v.x); l4.x = f2bf(v.x - bf2f(h4.x));
    h4.y = f2bf(v.y); l4.y = f2bf(v.y - bf2f(h4.y));
    h4.z = f2bf(v.z); l4.z = f2bf(v.z - bf2f(h4.z));
    h4.w = f2bf(v.w); l4.w = f2bf(v.w - bf2f(h4.w));
    ((ushort4*)hi)[i] = h4; ((ushort4*)lo)[i] = l4;
}

// ---- W [K][256] fp32 -> MFMA B-fragment layout, hi/lo bf16 planes ----
// out index o = (((kt*16+ct)*64+lane)*8+j);  k = kt*32+8*(lane>>4)+j, col = ct*16+(lane&15)
__global__ void repack_w_kernel(const float* __restrict__ W,
                                unsigned short* __restrict__ wbhi,
                                unsigned short* __restrict__ wblo)
{
    const int o = blockIdx.x * 256 + threadIdx.x;
    const int j = o & 7, ln = (o >> 3) & 63, ct = (o >> 9) & 15, kt = o >> 13;
    const int k = kt * 32 + 8 * (ln >> 4) + j;
    const int col = ct * 16 + (ln & 15);
    const float v = W[k * 256 + col];
    const unsigned short hb = f2bf(v);
    wbhi[o] = hb; wblo[o] = f2bf(v - bf2f(hb));
}

// =========================================================================
// MFMA GEMM h = x @ W ([N,K]@[K,256]) + per-head alpha reductions.
// Block = 256 thr = 4 waves = 64-node tile. Wave w owns col-tiles w*4..w*4+3
// (= head w). 3-pass hi/lo MFMA into shared fp32 acc. K-step = 32.
// C/D mapping (verified): col=lane&15, row=(lane>>4)*4+reg.
// =========================================================================
template<int K>
__global__ __launch_bounds__(256) void mfma_gemm_alpha(
    const unsigned short* __restrict__ xhi, const unsigned short* __restrict__ xlo,
    const unsigned short* __restrict__ wbhi, const unsigned short* __restrict__ wblo,
    const float* __restrict__ a_s, const float* __restrict__ a_d,
    unsigned short* __restrict__ hout,
    float* __restrict__ asrc, float* __restrict__ adst, int N)
{
    __shared__ unsigned short xa[8][512];     // [rt*2+plane][lane*8] A-frags
    __shared__ unsigned short wb[32][512];    // [ct*2+plane][lane*8] B-frags
    const int t = threadIdx.x, lane = t & 63, wid = t >> 6;
    const int n0 = blockIdx.x * 64;

    f32x4 acc[4][4];
#pragma unroll
    for (int rt = 0; rt < 4; ++rt)
#pragma unroll
        for (int q = 0; q < 4; ++q) acc[rt][q] = (f32x4){0.f, 0.f, 0.f, 0.f};

    for (int kt = 0; kt < K / 32; ++kt){
        __syncthreads();                      // previous iteration reads done
        // stage A-frags: 8 x 1KB, wave wid issues 2
#pragma unroll
        for (int ii = 0; ii < 2; ++ii){
            const int i = wid * 2 + ii;
            const int rt = i >> 1, plane = i & 1;
            int node = n0 + rt * 16 + (lane & 15);
            if (node > N - 1) node = N - 1;   // clamp; results discarded later
            const unsigned short* src = (plane ? xlo : xhi)
                + (size_t)node * K + kt * 32 + 8 * (lane >> 4);
            gload_lds16(src, &xa[i][0]);
        }
        // stage B-frags: 32 x 1KB, wave wid issues 8 (linear, coalesced)
#pragma unroll
        for (int ii = 0; ii < 8; ++ii){
            const int i = wid * 8 + ii;
            const int ct = i >> 1, plane = i & 1;
            const unsigned short* base = plane ? wblo : wbhi;
            gload_lds16(base + ((size_t)(kt * 16 + ct) * 64 + lane) * 8, &wb[i][0]);
        }
        __syncthreads();                      // drains vmcnt (incl. lds loads)

        bf16x8 a[4][2];
#pragma unroll
        for (int rt = 0; rt < 4; ++rt)
#pragma unroll
            for (int pl = 0; pl < 2; ++pl)
                a[rt][pl] = *(const bf16x8*)&xa[rt * 2 + pl][lane * 8];

#pragma unroll
        for (int q = 0; q < 4; ++q){
            const int cti = wid * 4 + q;
            const bf16x8 bhi = *(const bf16x8*)&wb[cti * 2 + 0][lane * 8];
            const bf16x8 blo = *(const bf16x8*)&wb[cti * 2 + 1][lane * 8];
#pragma unroll
            for (int rt = 0; rt < 4; ++rt){
                acc[rt][q] = __builtin_amdgcn_mfma_f32_16x16x32_bf16(a[rt][0], bhi, acc[rt][q], 0, 0, 0);
                acc[rt][q] = __builtin_amdgcn_mfma_f32_16x16x32_bf16(a[rt][1], bhi, acc[rt][q], 0, 0, 0);
                acc[rt][q] = __builtin_amdgcn_mfma_f32_16x16x32_bf16(a[rt][0], blo, acc[rt][q], 0, 0, 0);
            }
        }
    }

    // ---------------- epilogue: h store (bf16) + alpha reductions ----------------
    const int l15 = lane & 15, lg = lane >> 4;
    float avs[4], avd[4];
#pragma unroll
    for (int q = 0; q < 4; ++q){
        avs[q] = a_s[wid * 64 + q * 16 + l15];
        avd[q] = a_d[wid * 64 + q * 16 + l15];
    }
    float sp[4][4], dp[4][4];
#pragma unroll
    for (int rt = 0; rt < 4; ++rt){
#pragma unroll
        for (int reg = 0; reg < 4; ++reg){
            const int node = n0 + rt * 16 + lg * 4 + reg;
            float s = 0.f, d = 0.f;
            unsigned short hv[4];
#pragma unroll
            for (int q = 0; q < 4; ++q){
                const float v = acc[rt][q][reg];
                s = fmaf(v, avs[q], s); d = fmaf(v, avd[q], d);
                hv[q] = f2bf(v);
            }
            if (node < N){
#pragma unroll
                for (int q = 0; q < 4; ++q)
                    hout[(size_t)node * 256 + (wid * 4 + q) * 16 + l15] = hv[q];
            }
            sp[rt][reg] = s; dp[rt][reg] = d;
        }
    }
#pragma unroll
    for (int off = 1; off <= 8; off <<= 1){
#pragma unroll
        for (int rt = 0; rt < 4; ++rt)
#pragma unroll
            for (int reg = 0; reg < 4; ++reg){
                sp[rt][reg] += __shfl_xor(sp[rt][reg], off, 64);
                dp[rt][reg] += __shfl_xor(dp[rt][reg], off, 64);
            }
    }
    if (l15 == 0){
#pragma unroll
        for (int rt = 0; rt < 4; ++rt)
#pragma unroll
            for (int reg = 0; reg < 4; ++reg){
                const int node = n0 + rt * 16 + lg * 4 + reg;
                if (node < N){
                    asrc[(size_t)node * 4 + wid] = sp[rt][reg];
                    adst[(size_t)node * 4 + wid] = dp[rt][reg];
                }
            }
    }
}

// ============================ CSR build (once) ============================
__global__ void deg_init_kernel(int* __restrict__ deg, int N){
    int i = blockIdx.x * blockDim.x + threadIdx.x;
    if (i < N) deg[i] = 1;                        // self-loop
}

__global__ void deg_hist_kernel(const int* __restrict__ ei, int E, int* __restrict__ deg){
    int e = blockIdx.x * blockDim.x + threadIdx.x;
    if (e < E) atomicAdd(&deg[ei[E + e]], 1);
}

__global__ __launch_bounds__(256) void part_sum_kernel(const int* __restrict__ deg,
                                                       int* __restrict__ bsum, int N)
{
    __shared__ int red[256];
    const int t = threadIdx.x;
    const int i0 = blockIdx.x * 1024 + t * 4;
    int s = 0;
    if (i0 + 3 < N){
        const int4 v = *(const int4*)&deg[i0];
        s = v.x + v.y + v.z + v.w;
    } else {
#pragma unroll
        for (int j = 0; j < 4; ++j) if (i0 + j < N) s += deg[i0 + j];
    }
    red[t] = s; __syncthreads();
    for (int off = 128; off >= 1; off >>= 1){
        if (t < off) red[t] += red[t + off];
        __syncthreads();
    }
    if (t == 0) bsum[blockIdx.x] = red[0];
}

__global__ __launch_bounds__(256) void scan_part_kernel(int* __restrict__ bsum, int nb,
                                                        int* __restrict__ row, int N)
{
    __shared__ int sh[256];
    const int t = threadIdx.x;
    const int v = (t < nb) ? bsum[t] : 0;
    sh[t] = v; __syncthreads();
    for (int off = 1; off < 256; off <<= 1){
        int u = (t >= off) ? sh[t - off] : 0;
        __syncthreads();
        sh[t] += u;
        __syncthreads();
    }
    if (t < nb) bsum[t] = sh[t] - v;              // exclusive
    if (t == nb - 1) row[N] = sh[t];              // total = E + N
}

__global__ __launch_bounds__(256) void distribute_kernel(const int* __restrict__ deg,
    const int* __restrict__ bsum, int* __restrict__ row, int* __restrict__ cursor, int N)
{
    __shared__ int ts[256];
    const int t = threadIdx.x;
    const int i0 = blockIdx.x * 1024 + t * 4;
    int d[4]; int s = 0;
#pragma unroll
    for (int j = 0; j < 4; ++j){ d[j] = (i0 + j < N) ? deg[i0 + j] : 0; s += d[j]; }
    ts[t] = s; __syncthreads();
    for (int off = 1; off < 256; off <<= 1){
        int u = (t >= off) ? ts[t - off] : 0;
        __syncthreads();
        ts[t] += u;
        __syncthreads();
    }
    int base = bsum[blockIdx.x] + ts[t] - s;      // exclusive prefix for this thread
#pragma unroll
    for (int j = 0; j < 4; ++j){
        if (i0 + j < N){ row[i0 + j] = base; cursor[i0 + j] = base; base += d[j]; }
    }
}

__global__ void scatter_kernel(const int* __restrict__ ei, int E, int N,
                               int* __restrict__ cursor, int* __restrict__ csr)
{
    int e = blockIdx.x * blockDim.x + threadIdx.x;
    if (e >= E + N) return;
    int s, d;
    if (e < E){ s = ei[e]; d = ei[E + e]; } else { s = d = e - E; }
    int pos = atomicAdd(&cursor[d], 1);
    csr[pos] = s;
}

// =========================================================================
// Gather-aggregate per destination node: one wave per node, 4 waves/block.
// h plain [node][256] bf16; lane owns (head = lane>>4, channels 4*(lane&15)..+3).
// Phase A: lane-parallel p = exp(leakyrelu(e)) -> LDS + denom butterfly.
// Phase B: serial gather, 4-unrolled. Fused /denom + bias + BN + ELU (+res).
// Output: hi/lo bf16 planes.
// =========================================================================
#define DEG_CAP 128
__global__ __launch_bounds__(256) void agg4_kernel(
    const int* __restrict__ row, const int* __restrict__ csr,
    const float* __restrict__ asrc, const float* __restrict__ adst,
    const unsigned short* __restrict__ h,
    const float* __restrict__ b, const float* __restrict__ g,
    const float* __restrict__ be, const float* __restrict__ mean,
    const float* __restrict__ var,
    const unsigned short* __restrict__ reshi, const unsigned short* __restrict__ reslo,
    unsigned short* __restrict__ outhi, unsigned short* __restrict__ outlo, int N)
{
    __shared__ float4 plds[4][DEG_CAP];
    __shared__ int    slds[4][DEG_CAP];
    const int wid = threadIdx.x >> 6, lane = threadIdx.x & 63;
    const int node = blockIdx.x * 4 + wid;
    if (node >= N) return;
    const int beg = row[node], end = row[node + 1];
    const int head = lane >> 4, l15 = lane & 15;

    const float4 ad = *(const float4*)&adst[(size_t)node * 4];

    // ---- phase A ----
    float d0 = 0.f, d1 = 0.f, d2 = 0.f, d3 = 0.f;
    for (int i = beg + lane; i < end; i += 64){
        const int s = csr[i];
        const float4 as = *(const float4*)&asrc[(size_t)s * 4];
        float v0 = as.x + ad.x, v1 = as.y + ad.y, v2 = as.z + ad.z, v3 = as.w + ad.w;
        v0 = v0 > 0.f ? v0 : NEG_SLOPE * v0;
        v1 = v1 > 0.f ? v1 : NEG_SLOPE * v1;
        v2 = v2 > 0.f ? v2 : NEG_SLOPE * v2;
        v3 = v3 > 0.f ? v3 : NEG_SLOPE * v3;
        const float p0 = __expf(v0), p1 = __expf(v1);
        const float p2 = __expf(v2), p3 = __expf(v3);
        d0 += p0; d1 += p1; d2 += p2; d3 += p3;
        const int slot = i - beg;
        if (slot < DEG_CAP){
            plds[wid][slot] = make_float4(p0, p1, p2, p3);
            slds[wid][slot] = s;
        }
    }
    for (int off = 32; off >= 1; off >>= 1){
        d0 += __shfl_xor(d0, off, 64); d1 += __shfl_xor(d1, off, 64);
        d2 += __shfl_xor(d2, off, 64); d3 += __shfl_xor(d3, off, 64);
    }

    // ---- phase B ----
    float a0 = 0.f, a1 = 0.f, a2 = 0.f, a3 = 0.f;
    const int deg = end - beg;
    const int degc = deg < DEG_CAP ? deg : DEG_CAP;
    const float* pbase = (const float*)&plds[wid][0];

#define EDGE_BODY(slot)                                                        \
    {                                                                          \
        const float p_ = pbase[(slot) * 4 + head];                             \
        const int s_ = slds[wid][slot];                                        \
        const ushort4 hv_ = *(const ushort4*)&h[(size_t)s_ * 256 + lane * 4];  \
        a0 = fmaf(p_, bf2f(hv_.x), a0); a1 = fmaf(p_, bf2f(hv_.y), a1);        \
        a2 = fmaf(p_, bf2f(hv_.z), a2); a3 = fmaf(p_, bf2f(hv_.w), a3);        \
    }

    int i = 0;
    for (; i + 4 <= degc; i += 4){
        EDGE_BODY(i); EDGE_BODY(i + 1); EDGE_BODY(i + 2); EDGE_BODY(i + 3);
    }
    for (; i < degc; ++i) EDGE_BODY(i);
#undef EDGE_BODY

    // overflow path (deg > DEG_CAP): recompute p inline (statistically never)
    for (int jj = beg + DEG_CAP; jj < end; ++jj){
        const int s = csr[jj];
        const float4 as = *(const float4*)&asrc[(size_t)s * 4];
        float e0 = as.x + ad.x, e1 = as.y + ad.y, e2 = as.z + ad.z, e3 = as.w + ad.w;
        float eh = (head == 0) ? e0 : (head == 1) ? e1 : (head == 2) ? e2 : e3;
        eh = eh > 0.f ? eh : NEG_SLOPE * eh;
        const float p = __expf(eh);
        const ushort4 hv = *(const ushort4*)&h[(size_t)s * 256 + lane * 4];
        a0 = fmaf(p, bf2f(hv.x), a0); a1 = fmaf(p, bf2f(hv.y), a1);
        a2 = fmaf(p, bf2f(hv.z), a2); a3 = fmaf(p, bf2f(hv.w), a3);
    }

    // ---- fused epilogue ----
    const float dsel = (head == 0) ? d0 : (head == 1) ? d1 : (head == 2) ? d2 : d3;
    const float rdi = 1.f / dsel;
    const int c0 = head * 64 + 4 * l15;
    const float4 bv  = *(const float4*)&b[c0];
    const float4 gv  = *(const float4*)&g[c0];
    const float4 bev = *(const float4*)&be[c0];
    const float4 mv  = *(const float4*)&mean[c0];
    const float4 vv4 = *(const float4*)&var[c0];
    const float ava[4]  = {a0, a1, a2, a3};
    const float bva[4]  = {bv.x, bv.y, bv.z, bv.w};
    const float gva[4]  = {gv.x, gv.y, gv.z, gv.w};
    const float beva[4] = {bev.x, bev.y, bev.z, bev.w};
    const float mva[4]  = {mv.x, mv.y, mv.z, mv.w};
    const float vva[4]  = {vv4.x, vv4.y, vv4.z, vv4.w};
    float rh[4] = {0.f, 0.f, 0.f, 0.f};
    if (reshi){
        const ushort4 r1 = *(const ushort4*)&reshi[(size_t)node * 256 + c0];
        const ushort4 r2 = *(const ushort4*)&reslo[(size_t)node * 256 + c0];
        rh[0] = bf2f(r1.x) + bf2f(r2.x); rh[1] = bf2f(r1.y) + bf2f(r2.y);
        rh[2] = bf2f(r1.z) + bf2f(r2.z); rh[3] = bf2f(r1.w) + bf2f(r2.w);
    }
    unsigned short hos[4], los[4];
#pragma unroll
    for (int j = 0; j < 4; ++j){
        float vvv = ava[j] * rdi + bva[j];
        vvv = (vvv - mva[j]) * (gva[j] * rsqrtf(vva[j] + BN_EPS)) + beva[j];
        vvv = vvv > 0.f ? vvv : (__expf(vvv) - 1.f);
        vvv += rh[j];
        const unsigned short hb = f2bf(vvv);
        hos[j] = hb; los[j] = f2bf(vvv - bf2f(hb));
    }
    ushort4 ho, lo4;
    ho.x = hos[0];  ho.y = hos[1];  ho.z = hos[2];  ho.w = hos[3];
    lo4.x = los[0]; lo4.y = los[1]; lo4.z = los[2]; lo4.w = los[3];
    *(ushort4*)&outhi[(size_t)node * 256 + c0] = ho;
    *(ushort4*)&outlo[(size_t)node * 256 + c0] = lo4;
}

// ------------------------- layer 2 (heads=1, C=1) -------------------------
__global__ __launch_bounds__(256) void gemm2_kernel(
    const unsigned short* __restrict__ xhi, const unsigned short* __restrict__ xlo,
    const float* __restrict__ W2, float* __restrict__ h2, int N)
{
    const int wid = threadIdx.x >> 6, lane = threadIdx.x & 63;
    const int n = blockIdx.x * 4 + wid;
    if (n >= N) return;
    float sum = 0.f;
#pragma unroll
    for (int i = 0; i < 4; ++i){
        const int c = i * 64 + lane;
        sum += (bf2f(xhi[(size_t)n * 256 + c]) + bf2f(xlo[(size_t)n * 256 + c])) * W2[c];
    }
    for (int off = 32; off >= 1; off >>= 1) sum += __shfl_xor(sum, off, 64);
    if (lane == 0) h2[n] = sum;
}

__global__ void agg2_kernel(const int* __restrict__ row, const int* __restrict__ csr,
                            const float* __restrict__ h2,
                            const float* __restrict__ as2, const float* __restrict__ ad2,
                            const float* __restrict__ b2, float* __restrict__ out, int N)
{
    const int n = blockIdx.x * blockDim.x + threadIdx.x;
    if (n >= N) return;
    const float A_s = as2[0];
    const float hd  = h2[n] * ad2[0];
    const int beg = row[n], end = row[n + 1];
    float den = 0.f, acc = 0.f;
    for (int i = beg; i < end; ++i){
        const float hv = h2[csr[i]];
        float a = fmaf(A_s, hv, hd);
        a = a > 0.f ? a : NEG_SLOPE * a;
        const float p = __expf(a);
        den += p; acc = fmaf(p, hv, acc);
    }
    out[n] = acc / den + b2[0];
}

// =========================================================================
extern "C" void kernel_launch(void* const* d_in, const int* in_sizes, int n_in,
                              void* d_out, int out_size, void* d_ws, size_t ws_size,
                              hipStream_t stream)
{
    const float* x   = (const float*)d_in[0];
    const int*   ei  = (const int*)  d_in[1];
    const float* W0  = (const float*)d_in[2];
    const float* as0 = (const float*)d_in[3];
    const float* ad0 = (const float*)d_in[4];
    const float* b0  = (const float*)d_in[5];
    const float* W1  = (const float*)d_in[6];
    const float* as1 = (const float*)d_in[7];
    const float* ad1 = (const float*)d_in[8];
    const float* b1  = (const float*)d_in[9];
    const float* W2  = (const float*)d_in[10];
    const float* as2 = (const float*)d_in[11];
    const float* ad2 = (const float*)d_in[12];
    const float* b2  = (const float*)d_in[13];
    const float* g0  = (const float*)d_in[14];
    const float* be0 = (const float*)d_in[15];
    const float* m0  = (const float*)d_in[16];
    const float* v0  = (const float*)d_in[17];
    const float* g1  = (const float*)d_in[18];
    const float* be1 = (const float*)d_in[19];
    const float* m1  = (const float*)d_in[20];
    const float* v1  = (const float*)d_in[21];

    const int N = in_sizes[0] / 128;
    const int E = in_sizes[1] / 2;
    const int EN = E + N;

    // ---- workspace layout (hi/lo activation planes; P1hi aliases X0) ----
    char* w = (char*)d_ws;
    unsigned short* H    = (unsigned short*)w;  w += (size_t)N * 256 * 2;  // h bf16 [N][256]
    unsigned short* X0hi = (unsigned short*)w;                              // N*128 bf16
    unsigned short* X0lo = X0hi + (size_t)N * 128;
    unsigned short* P1hi = X0hi;                // alias: X0 dead after layer-0 GEMM
    w += (size_t)N * 256 * 2;
    unsigned short* P0hi = (unsigned short*)w;  w += (size_t)N * 256 * 2;
    unsigned short* P0lo = (unsigned short*)w;  w += (size_t)N * 256 * 2;
    unsigned short* P1lo = (unsigned short*)w;  w += (size_t)N * 256 * 2;
    float*    asrc   = (float*)w;   w += (size_t)N * 4 * 4;
    float*    adst   = (float*)w;   w += (size_t)N * 4 * 4;
    int*      deg    = (int*)w;     w += (size_t)N * 4;
    int*      cursor = (int*)w;     w += (size_t)N * 4;
    int*      csr    = (int*)w;     w += (size_t)EN * 4;
    float*    h2     = (float*)w;   w += (size_t)N * 4;
    int*      bsum   = (int*)w;     w += 1024;
    unsigned short* Wb0hi = (unsigned short*)w; w += (size_t)128 * 256 * 2;
    unsigned short* Wb0lo = (unsigned short*)w; w += (size_t)128 * 256 * 2;
    unsigned short* Wb1hi = (unsigned short*)w; w += (size_t)256 * 256 * 2;
    unsigned short* Wb1lo = (unsigned short*)w; w += (size_t)256 * 256 * 2;
    int*      rowp   = (int*)w;     w += (size_t)(N + 1) * 4;   // last (odd size)

    const int gN64  = (N + 63) / 64;
    const int gN4   = (N + 3) / 4;
    const int gNt   = (N + 255) / 256;
    const int gE    = (E + 255) / 256;
    const int gEN   = (EN + 255) / 256;
    const int nb    = (N + 1023) / 1024;

    // ---------------- one-time prep: hi/lo planes, W repack, CSR ----------------
    conv_hilo_kernel<<<(N * 128 / 4 + 255) / 256, 256, 0, stream>>>(x, X0hi, X0lo, N * 128 / 4);
    repack_w_kernel<<<128, 256, 0, stream>>>(W0, Wb0hi, Wb0lo);
    repack_w_kernel<<<256, 256, 0, stream>>>(W1, Wb1hi, Wb1lo);
    deg_init_kernel<<<gNt, 256, 0, stream>>>(deg, N);
    deg_hist_kernel<<<gE, 256, 0, stream>>>(ei, E, deg);
    part_sum_kernel<<<nb, 256, 0, stream>>>(deg, bsum, N);
    scan_part_kernel<<<1, 256, 0, stream>>>(bsum, nb, rowp, N);
    distribute_kernel<<<nb, 256, 0, stream>>>(deg, bsum, rowp, cursor, N);
    scatter_kernel<<<gEN, 256, 0, stream>>>(ei, E, N, cursor, csr);

    // ---------------- layer 0 ----------------
    mfma_gemm_alpha<128><<<gN64, 256, 0, stream>>>(X0hi, X0lo, Wb0hi, Wb0lo,
                                                   as0, ad0, H, asrc, adst, N);
    agg4_kernel<<<gN4, 256, 0, stream>>>(rowp, csr, asrc, adst, H,
                                         b0, g0, be0, m0, v0,
                                         nullptr, nullptr, P0hi, P0lo, N);

    // ---------------- layer 1 ----------------
    mfma_gemm_alpha<256><<<gN64, 256, 0, stream>>>(P0hi, P0lo, Wb1hi, Wb1lo,
                                                   as1, ad1, H, asrc, adst, N);
    agg4_kernel<<<gN4, 256, 0, stream>>>(rowp, csr, asrc, adst, H,
                                         b1, g1, be1, m1, v1,
                                         P0hi, P0lo, P1hi, P1lo, N);

    // ---------------- layer 2 ----------------
    gemm2_kernel<<<gN4, 256, 0, stream>>>(P1hi, P1lo, W2, h2, N);
    agg2_kernel<<<gNt, 256, 0, stream>>>(rowp, csr, h2, as2, ad2, b2, (float*)d_out, N);
}